// Round 8
// baseline (148.157 us; speedup 1.0000x reference)
//
#include <hip/hip_runtime.h>
#include <hip/hip_fp16.h>

// GCN 2-layer forward. N=100000 nodes, E=1600000 directed edges.
// out[c] = relu( dinv[c] * ( sum_{r->c} g[r] + g[c] ) + b ),  g = (x@W)*dinv
// dinv = rsqrt(indeg+1) (self-loops folded in analytically).
// Round 18: gather-before-matmul for layer 1. Since aggregation commutes with
// the linear map, layer 1 gathers xd = fp16(x*dinv) (16 feats, 32B rows,
// 3.2MB -> fits a 4MB per-XCD L2) and applies W1 AFTER aggregation inside
// the gather kernel; previously it gathered g1 = (x@W1)*dinv (32 feats, 64B
// rows, 6.4MB -> L3-bound). Halves gather1 bytes + VMEM ops, converts L3
// misses to L2 hits. Sort's fused mm1 becomes a pure fp16 scale. Both gather
// loops deepened to 8 edges in flight (padded CSR, branchless).
// Negative results bank (do NOT retry): LDS-atomic accumulation (r11/12);
// degree-ranked perm (r13: gathers not divergence-bound); global counting
// scatter (r14: 17x write amp); 32KB col cache in fill / NBUCKET=782 (r15).

constexpr int NN  = 100000;
constexpr int FIN = 16;
constexpr int FH  = 32;   // hidden
constexpr int FO  = 16;   // layer-2 out

constexpr int BK      = 256;                     // nodes per bucket (col>>8)
constexpr int NBUCKET = (NN + BK - 1) / BK;      // 391
constexpr int CHUNK   = 8192;                    // edges per block (fill)
constexpr int CAP     = 5632;                    // bucket capacity (mean 4092 + pad, +18 sigma)

static __device__ __forceinline__ int pack2(float a, float b) {
    __half2 t = __float22half2_rn(make_float2(a, b));
    return *reinterpret_cast<int*>(&t);
}
static __device__ __forceinline__ float2 unpack2(int v) {
    __half2 t = *reinterpret_cast<__half2*>(&v);
    return __half22float2(t);
}

// ---- init: bcursor[b] = b*CAP; zero sentinel rows xd[NN], g2[NN] ----
__global__ void init_kernel(int* __restrict__ bcursor,
                            __half* __restrict__ xd, __half* __restrict__ g2) {
    int b = blockIdx.x * blockDim.x + threadIdx.x;
    if (b < NBUCKET) bcursor[b] = b * CAP;
    if (b < 2) ((int4*)(xd + (long long)NN * FIN))[b] = make_int4(0, 0, 0, 0);
    else if (b < 4) ((int4*)(g2 + (long long)NN * FO))[b - 2] = make_int4(0, 0, 0, 0);
}

// ---- phase A: bucket fill into fixed segments. Per-block run reservation. ----
__global__ __launch_bounds__(512) void bucket_fill_kernel(
        const int* __restrict__ row, const int* __restrict__ col,
        int* __restrict__ bcursor, int* __restrict__ srow, int E) {
    __shared__ int bcnt[NBUCKET];
    __shared__ int bcur[NBUCKET];
    int t = threadIdx.x;
    int e0 = blockIdx.x * CHUNK;
    int m = E - e0; if (m > CHUNK) m = CHUNK;
    for (int b = t; b < NBUCKET; b += 512) bcnt[b] = 0;
    __syncthreads();
    for (int i = t; i < m; i += 512)
        atomicAdd(&bcnt[col[e0 + i] >> 8], 1);
    __syncthreads();
    for (int b = t; b < NBUCKET; b += 512) {
        int v = bcnt[b];
        bcur[b] = v ? atomicAdd(&bcursor[b], v) : 0;   // contiguous run for this block
    }
    __syncthreads();
    for (int i = t; i < m; i += 512) {
        int c = col[e0 + i];
        int r = row[e0 + i];
        int p = atomicAdd(&bcur[c >> 8], 1);
        srow[p] = ((c & (BK - 1)) << 17) | r;          // pack (c_local, r); r < 2^17
    }
}

// ---- phase B: per-bucket LDS counting sort; emits off/cnt/dinv AND
// xd = fp16(x * dinv) rows (scale only; W1 moved into the gather kernel).
// 512 threads; padded offsets (multiple of 4) with sentinel NN in pads.
__global__ __launch_bounds__(512) void bucket_sort_scale_kernel(
        const int* __restrict__ bcursor, int* __restrict__ srow,
        int* __restrict__ off, int* __restrict__ cnt, float* __restrict__ dinv,
        const float* __restrict__ x, __half* __restrict__ xd, int n) {
    __shared__ int ebuf[CAP];
    __shared__ int sorted[CAP];
    __shared__ int cnt2[BK];
    __shared__ float sdi[BK];
    __shared__ int wsum[4];
    __shared__ int wbase[4];
    __shared__ int Mtot;
    int t = threadIdx.x;
    int lo = blockIdx.x << 8;
    int nodes = n - lo; if (nodes > BK) nodes = BK;
    int s0 = blockIdx.x * CAP;
    int m = bcursor[blockIdx.x] - s0;                  // total edges in this bucket
    if (m > CAP) m = CAP;                              // paranoia guard (never hit)
    if (m < 0)  m = 0;
    for (int i = t; i < m; i += 512) ebuf[i] = srow[s0 + i];
    if (t < BK) cnt2[t] = 0;
    __syncthreads();
    for (int i = t; i < m; i += 512) atomicAdd(&cnt2[ebuf[i] >> 17], 1);
    __syncthreads();
    int v = 0, pv = 0, s = 0, excl = 0;
    if (t < BK) {
        v  = cnt2[t];
        pv = (v + 3) & ~3;                             // padded count
        s  = pv;
        #pragma unroll
        for (int d = 1; d < 64; d <<= 1) {             // inclusive wave scan
            int u = __shfl_up(s, d, 64);
            if ((t & 63) >= d) s += u;
        }
        if ((t & 63) == 63) wsum[t >> 6] = s;
    }
    __syncthreads();
    if (t < 4) {
        int b = 0;
        for (int k = 0; k < t; k++) b += wsum[k];
        wbase[t] = b;
    }
    __syncthreads();
    if (t < BK) {
        excl = s + wbase[t >> 6] - pv;                 // exclusive padded prefix
        cnt2[t] = excl;                                // cursor for scatter
        float di = rsqrtf((float)v + 1.0f);
        sdi[t] = di;
        if (t < nodes) {
            off[lo + t]  = s0 + excl;
            cnt[lo + t]  = v;
            dinv[lo + t] = di;
        }
        if (t == BK - 1) Mtot = excl + pv;             // total padded length
    }
    __syncthreads();
    for (int i = t; i < m; i += 512) {
        int pvv = ebuf[i];
        int p = atomicAdd(&cnt2[pvv >> 17], 1);
        sorted[p] = pvv & 0x1FFFF;
    }
    __syncthreads();
    if (t < BK) {                                      // sentinel pads
        for (int p = excl + v; p < excl + pv; p++) sorted[p] = NN;
    }
    __syncthreads();
    int M = Mtot; if (M > CAP) M = CAP;
    for (int i = t; i < M; i += 512) srow[s0 + i] = sorted[i];
    // ---- xd[nd] = fp16( x[nd] * di ): lane=t>>8 writes 8 feats (one int4) ----
    int lane = t >> 8;                                 // 0 or 1
    int nd0  = t & 255;
    if (nd0 < nodes) {
        int nd = lo + nd0;
        float di = sdi[nd0];
        const float4* xv = (const float4*)(x + (long long)nd * FIN) + lane * 2;
        float4 v0 = xv[0], v1 = xv[1];
        ((int4*)(xd + (long long)nd * FIN))[lane] =
            make_int4(pack2(v0.x * di, v0.y * di), pack2(v0.z * di, v0.w * di),
                      pack2(v1.x * di, v1.y * di), pack2(v1.z * di, v1.w * di));
    }
}

// ---- fused layer1: gather xd (16-feat fp16 rows, L2-resident) + W1 + relu
// + bias + mm2 + scale -> g2 (fp16). 256 threads = 128 nodes x 2 lanes
// (lane = 8 feats = int4 = 16B). Padded CSR, 8 edges in flight. ----
__global__ __launch_bounds__(256) void gather1_kernel(
        const int* __restrict__ off, const int* __restrict__ cnt,
        const int* __restrict__ srow, const __half* __restrict__ xd,
        const float* __restrict__ dinv, const float* __restrict__ b1,
        const float* __restrict__ W1, const float* __restrict__ W2,
        __half* __restrict__ g2, int n) {
    __shared__ float w1[FIN * FH];         // 16x32
    __shared__ float w2[FH * FO];          // 32x16
    __shared__ float bb[FH];
    int t = threadIdx.x;
    for (int i = t; i < FIN * FH; i += 256) w1[i] = W1[i];
    for (int i = t; i < FH * FO; i += 256) w2[i] = W2[i];
    if (t < FH) bb[t] = b1[t];
    int node = blockIdx.x * 128 + (t >> 1);
    int q = t & 1;                         // 8-feat group
    bool live = node < n;
    float acc[8] = {0.f,0.f,0.f,0.f,0.f,0.f,0.f,0.f};
    float di = 0.f;
    if (live) {
        di = dinv[node];
        {   // self-loop seed
            int4 raw = ((const int4*)(xd + (long long)node * FIN))[q];
            float2 f0 = unpack2(raw.x), f1 = unpack2(raw.y);
            float2 f2 = unpack2(raw.z), f3 = unpack2(raw.w);
            acc[0] = f0.x; acc[1] = f0.y; acc[2] = f1.x; acc[3] = f1.y;
            acc[4] = f2.x; acc[5] = f2.y; acc[6] = f3.x; acc[7] = f3.y;
        }
        int s = off[node];
        int m = cnt[node];
        int i = 0;
        for (; i + 7 < m; i += 8) {        // 8 rows in flight
            int4 ix0 = *(const int4*)(srow + s + i);
            int4 ix1 = *(const int4*)(srow + s + i + 4);
            int4 ra = ((const int4*)(xd + (long long)ix0.x * FIN))[q];
            int4 rb = ((const int4*)(xd + (long long)ix0.y * FIN))[q];
            int4 rc = ((const int4*)(xd + (long long)ix0.z * FIN))[q];
            int4 rd = ((const int4*)(xd + (long long)ix0.w * FIN))[q];
            int4 re = ((const int4*)(xd + (long long)ix1.x * FIN))[q];
            int4 rf = ((const int4*)(xd + (long long)ix1.y * FIN))[q];
            int4 rg = ((const int4*)(xd + (long long)ix1.z * FIN))[q];
            int4 rh = ((const int4*)(xd + (long long)ix1.w * FIN))[q];
            float2 u;
            u = unpack2(ra.x); acc[0] += u.x; acc[1] += u.y;
            u = unpack2(ra.y); acc[2] += u.x; acc[3] += u.y;
            u = unpack2(ra.z); acc[4] += u.x; acc[5] += u.y;
            u = unpack2(ra.w); acc[6] += u.x; acc[7] += u.y;
            u = unpack2(rb.x); acc[0] += u.x; acc[1] += u.y;
            u = unpack2(rb.y); acc[2] += u.x; acc[3] += u.y;
            u = unpack2(rb.z); acc[4] += u.x; acc[5] += u.y;
            u = unpack2(rb.w); acc[6] += u.x; acc[7] += u.y;
            u = unpack2(rc.x); acc[0] += u.x; acc[1] += u.y;
            u = unpack2(rc.y); acc[2] += u.x; acc[3] += u.y;
            u = unpack2(rc.z); acc[4] += u.x; acc[5] += u.y;
            u = unpack2(rc.w); acc[6] += u.x; acc[7] += u.y;
            u = unpack2(rd.x); acc[0] += u.x; acc[1] += u.y;
            u = unpack2(rd.y); acc[2] += u.x; acc[3] += u.y;
            u = unpack2(rd.z); acc[4] += u.x; acc[5] += u.y;
            u = unpack2(rd.w); acc[6] += u.x; acc[7] += u.y;
            u = unpack2(re.x); acc[0] += u.x; acc[1] += u.y;
            u = unpack2(re.y); acc[2] += u.x; acc[3] += u.y;
            u = unpack2(re.z); acc[4] += u.x; acc[5] += u.y;
            u = unpack2(re.w); acc[6] += u.x; acc[7] += u.y;
            u = unpack2(rf.x); acc[0] += u.x; acc[1] += u.y;
            u = unpack2(rf.y); acc[2] += u.x; acc[3] += u.y;
            u = unpack2(rf.z); acc[4] += u.x; acc[5] += u.y;
            u = unpack2(rf.w); acc[6] += u.x; acc[7] += u.y;
            u = unpack2(rg.x); acc[0] += u.x; acc[1] += u.y;
            u = unpack2(rg.y); acc[2] += u.x; acc[3] += u.y;
            u = unpack2(rg.z); acc[4] += u.x; acc[5] += u.y;
            u = unpack2(rg.w); acc[6] += u.x; acc[7] += u.y;
            u = unpack2(rh.x); acc[0] += u.x; acc[1] += u.y;
            u = unpack2(rh.y); acc[2] += u.x; acc[3] += u.y;
            u = unpack2(rh.z); acc[4] += u.x; acc[5] += u.y;
            u = unpack2(rh.w); acc[6] += u.x; acc[7] += u.y;
        }
        for (; i < m; i += 4) {            // remainder is 0 or 4 (padded)
            int4 ix = *(const int4*)(srow + s + i);
            int4 ra = ((const int4*)(xd + (long long)ix.x * FIN))[q];
            int4 rb = ((const int4*)(xd + (long long)ix.y * FIN))[q];
            int4 rc = ((const int4*)(xd + (long long)ix.z * FIN))[q];
            int4 rd = ((const int4*)(xd + (long long)ix.w * FIN))[q];
            float2 u;
            u = unpack2(ra.x); acc[0] += u.x; acc[1] += u.y;
            u = unpack2(ra.y); acc[2] += u.x; acc[3] += u.y;
            u = unpack2(ra.z); acc[4] += u.x; acc[5] += u.y;
            u = unpack2(ra.w); acc[6] += u.x; acc[7] += u.y;
            u = unpack2(rb.x); acc[0] += u.x; acc[1] += u.y;
            u = unpack2(rb.y); acc[2] += u.x; acc[3] += u.y;
            u = unpack2(rb.z); acc[4] += u.x; acc[5] += u.y;
            u = unpack2(rb.w); acc[6] += u.x; acc[7] += u.y;
            u = unpack2(rc.x); acc[0] += u.x; acc[1] += u.y;
            u = unpack2(rc.y); acc[2] += u.x; acc[3] += u.y;
            u = unpack2(rc.z); acc[4] += u.x; acc[5] += u.y;
            u = unpack2(rc.w); acc[6] += u.x; acc[7] += u.y;
            u = unpack2(rd.x); acc[0] += u.x; acc[1] += u.y;
            u = unpack2(rd.y); acc[2] += u.x; acc[3] += u.y;
            u = unpack2(rd.z); acc[4] += u.x; acc[5] += u.y;
            u = unpack2(rd.w); acc[6] += u.x; acc[7] += u.y;
        }
    }
    __syncthreads();                       // weights loaded
    if (live) {
        // assemble full 16-feat aggregate: other half from partner lane
        float a[FIN];
        #pragma unroll
        for (int j = 0; j < 8; j++) {
            float o = __shfl_xor(acc[j], 1);
            a[8 * q + j] = acc[j];
            a[8 * (1 - q) + j] = o;
        }
        // lane q computes hidden k = 16q..16q+15: h -> relu -> mm2 partials
        float o[FO];
        #pragma unroll
        for (int kk = 0; kk < FO; kk++) o[kk] = 0.f;
        int k0 = 16 * q;
        #pragma unroll
        for (int k = 0; k < 16; k++) {
            float h = 0.f;
            #pragma unroll
            for (int i2 = 0; i2 < FIN; i2++) h += a[i2] * w1[i2 * FH + k0 + k];
            float x1 = h * di + bb[k0 + k];
            x1 = x1 > 0.f ? x1 : 0.f;
            const float* wr = w2 + (k0 + k) * FO;
            #pragma unroll
            for (int kk = 0; kk < FO; kk++) o[kk] += x1 * wr[kk];
        }
        #pragma unroll
        for (int kk = 0; kk < FO; kk++) o[kk] += __shfl_xor(o[kk], 1);
        ((int4*)(g2 + (long long)node * FO))[q] =
            make_int4(pack2(o[8*q]   * di, o[8*q+1] * di),
                      pack2(o[8*q+2] * di, o[8*q+3] * di),
                      pack2(o[8*q+4] * di, o[8*q+5] * di),
                      pack2(o[8*q+6] * di, o[8*q+7] * di));
    }
}

// ---- fused gather layer2 (fp16 rows) + relu/bias + fc -> out ----
// block = 256 threads = 128 nodes x 2 lanes; padded CSR, 8 edges in flight.
__global__ __launch_bounds__(256) void gather_fc_kernel(
        const int* __restrict__ off, const int* __restrict__ cnt,
        const int* __restrict__ srow, const __half* __restrict__ g2,
        const float* __restrict__ dinv, const float* __restrict__ b2,
        const float* __restrict__ fcW, const float* __restrict__ fcb,
        float* __restrict__ out, int n) {
    __shared__ float w[FO];
    __shared__ float bb[FO];
    __shared__ float fb;
    int t = threadIdx.x;
    if (t < FO) { w[t] = fcW[t]; bb[t] = b2[t]; }
    if (t == 0) fb = fcb[0];
    __syncthreads();
    int node = blockIdx.x * 128 + (t >> 1);
    int q = t & 1;
    if (node >= n) return;
    float di = dinv[node];
    float acc[8];
    {   // self-loop seed
        int4 raw = ((const int4*)(g2 + (long long)node * FO))[q];
        float2 f0 = unpack2(raw.x), f1 = unpack2(raw.y);
        float2 f2 = unpack2(raw.z), f3 = unpack2(raw.w);
        acc[0] = f0.x; acc[1] = f0.y; acc[2] = f1.x; acc[3] = f1.y;
        acc[4] = f2.x; acc[5] = f2.y; acc[6] = f3.x; acc[7] = f3.y;
    }
    int s = off[node];
    int m = cnt[node];
    int i = 0;
    for (; i + 7 < m; i += 8) {            // 8 rows in flight
        int4 ix0 = *(const int4*)(srow + s + i);
        int4 ix1 = *(const int4*)(srow + s + i + 4);
        int4 ra = ((const int4*)(g2 + (long long)ix0.x * FO))[q];
        int4 rb = ((const int4*)(g2 + (long long)ix0.y * FO))[q];
        int4 rc = ((const int4*)(g2 + (long long)ix0.z * FO))[q];
        int4 rd = ((const int4*)(g2 + (long long)ix0.w * FO))[q];
        int4 re = ((const int4*)(g2 + (long long)ix1.x * FO))[q];
        int4 rf = ((const int4*)(g2 + (long long)ix1.y * FO))[q];
        int4 rg = ((const int4*)(g2 + (long long)ix1.z * FO))[q];
        int4 rh = ((const int4*)(g2 + (long long)ix1.w * FO))[q];
        float2 u;
        u = unpack2(ra.x); acc[0] += u.x; acc[1] += u.y;
        u = unpack2(ra.y); acc[2] += u.x; acc[3] += u.y;
        u = unpack2(ra.z); acc[4] += u.x; acc[5] += u.y;
        u = unpack2(ra.w); acc[6] += u.x; acc[7] += u.y;
        u = unpack2(rb.x); acc[0] += u.x; acc[1] += u.y;
        u = unpack2(rb.y); acc[2] += u.x; acc[3] += u.y;
        u = unpack2(rb.z); acc[4] += u.x; acc[5] += u.y;
        u = unpack2(rb.w); acc[6] += u.x; acc[7] += u.y;
        u = unpack2(rc.x); acc[0] += u.x; acc[1] += u.y;
        u = unpack2(rc.y); acc[2] += u.x; acc[3] += u.y;
        u = unpack2(rc.z); acc[4] += u.x; acc[5] += u.y;
        u = unpack2(rc.w); acc[6] += u.x; acc[7] += u.y;
        u = unpack2(rd.x); acc[0] += u.x; acc[1] += u.y;
        u = unpack2(rd.y); acc[2] += u.x; acc[3] += u.y;
        u = unpack2(rd.z); acc[4] += u.x; acc[5] += u.y;
        u = unpack2(rd.w); acc[6] += u.x; acc[7] += u.y;
        u = unpack2(re.x); acc[0] += u.x; acc[1] += u.y;
        u = unpack2(re.y); acc[2] += u.x; acc[3] += u.y;
        u = unpack2(re.z); acc[4] += u.x; acc[5] += u.y;
        u = unpack2(re.w); acc[6] += u.x; acc[7] += u.y;
        u = unpack2(rf.x); acc[0] += u.x; acc[1] += u.y;
        u = unpack2(rf.y); acc[2] += u.x; acc[3] += u.y;
        u = unpack2(rf.z); acc[4] += u.x; acc[5] += u.y;
        u = unpack2(rf.w); acc[6] += u.x; acc[7] += u.y;
        u = unpack2(rg.x); acc[0] += u.x; acc[1] += u.y;
        u = unpack2(rg.y); acc[2] += u.x; acc[3] += u.y;
        u = unpack2(rg.z); acc[4] += u.x; acc[5] += u.y;
        u = unpack2(rg.w); acc[6] += u.x; acc[7] += u.y;
        u = unpack2(rh.x); acc[0] += u.x; acc[1] += u.y;
        u = unpack2(rh.y); acc[2] += u.x; acc[3] += u.y;
        u = unpack2(rh.z); acc[4] += u.x; acc[5] += u.y;
        u = unpack2(rh.w); acc[6] += u.x; acc[7] += u.y;
    }
    for (; i < m; i += 4) {                // remainder is 0 or 4 (padded)
        int4 ix = *(const int4*)(srow + s + i);
        int4 ra = ((const int4*)(g2 + (long long)ix.x * FO))[q];
        int4 rb = ((const int4*)(g2 + (long long)ix.y * FO))[q];
        int4 rc = ((const int4*)(g2 + (long long)ix.z * FO))[q];
        int4 rd = ((const int4*)(g2 + (long long)ix.w * FO))[q];
        float2 u;
        u = unpack2(ra.x); acc[0] += u.x; acc[1] += u.y;
        u = unpack2(ra.y); acc[2] += u.x; acc[3] += u.y;
        u = unpack2(ra.z); acc[4] += u.x; acc[5] += u.y;
        u = unpack2(ra.w); acc[6] += u.x; acc[7] += u.y;
        u = unpack2(rb.x); acc[0] += u.x; acc[1] += u.y;
        u = unpack2(rb.y); acc[2] += u.x; acc[3] += u.y;
        u = unpack2(rb.z); acc[4] += u.x; acc[5] += u.y;
        u = unpack2(rb.w); acc[6] += u.x; acc[7] += u.y;
        u = unpack2(rc.x); acc[0] += u.x; acc[1] += u.y;
        u = unpack2(rc.y); acc[2] += u.x; acc[3] += u.y;
        u = unpack2(rc.z); acc[4] += u.x; acc[5] += u.y;
        u = unpack2(rc.w); acc[6] += u.x; acc[7] += u.y;
        u = unpack2(rd.x); acc[0] += u.x; acc[1] += u.y;
        u = unpack2(rd.y); acc[2] += u.x; acc[3] += u.y;
        u = unpack2(rd.z); acc[4] += u.x; acc[5] += u.y;
        u = unpack2(rd.w); acc[6] += u.x; acc[7] += u.y;
    }
    // x2 = relu(acc*di + b2[8q..]); partial dot with fcW
    float p = 0.f;
    #pragma unroll
    for (int j = 0; j < 8; j++) {
        float a = acc[j] * di + bb[8*q + j];
        p += (a > 0.f ? a : 0.f) * w[8*q + j];
    }
    p += __shfl_down(p, 1, 2);             // reduce the node's 2 lanes
    if (q == 0) out[node] = p + fb;
}

extern "C" void kernel_launch(void* const* d_in, const int* in_sizes, int n_in,
                              void* d_out, int out_size, void* d_ws, size_t ws_size,
                              hipStream_t stream) {
    const int*   edge = (const int*)d_in[0];        // [2, E] int32
    const float* x    = (const float*)d_in[1];      // [N, 16]
    const float* W1   = (const float*)d_in[2];      // [16, 32]
    const float* b1   = (const float*)d_in[3];      // [32]
    const float* W2   = (const float*)d_in[4];      // [32, 16]
    const float* b2   = (const float*)d_in[5];      // [16]
    const float* fcW  = (const float*)d_in[6];      // [16, 1]
    const float* fcb  = (const float*)d_in[7];      // [1]
    float* out = (float*)d_out;

    const int E = in_sizes[0] / 2;                  // 1600000
    const int n = NN;
    const int* row = edge;
    const int* col = edge + E;

    // workspace layout (4-byte units), regions 128-elem aligned:
    const size_t nA = (size_t)((n + 127) & ~127);
    char* wsb = (char*)d_ws;
    int*   cnt     = (int*)wsb;                     // n ints (per-node degree)
    int*   off     = cnt + nA;                      // n ints (padded CSR offsets)
    float* dinv    = (float*)(off + nA);            // n floats
    int*   bcursor = (int*)(dinv + nA);             // NBUCKET ints (pad 512)
    int*   srow    = bcursor + 512;                 // (NBUCKET+1)*CAP ints (+slack seg)
    int*   srowEnd = srow + (size_t)(NBUCKET + 1) * CAP;
    __half* xd     = (__half*)srowEnd;              // (n+1)*FIN halfs (3.2MB, L2-fit)
    __half* g2     = xd + (size_t)(n + 1) * FIN;    // (n+1)*FO halfs (3.2MB, L2-fit)

    const int nChunkBlocks = (E + CHUNK - 1) / CHUNK;   // 196

    // 1. bcursor[b] = b*CAP; zero sentinel rows
    init_kernel<<<2, 256, 0, stream>>>(bcursor, xd, g2);
    // 2. phase A: bucket fill into fixed segments; per-block run reservation
    bucket_fill_kernel<<<nChunkBlocks, 512, 0, stream>>>(row, col, bcursor, srow, E);
    // 3. phase B: per-bucket LDS counting sort (padded offsets) + xd scale
    bucket_sort_scale_kernel<<<NBUCKET, 512, 0, stream>>>(bcursor, srow, off, cnt, dinv, x, xd, n);
    // 4. fused gather1 (xd) + W1 + relu/bias + mm2 + scale -> g2  (128 nodes/block)
    gather1_kernel<<<(n + 127) / 128, 256, 0, stream>>>(off, cnt, srow, xd, dinv, b1, W1, W2, g2, n);
    // 5. fused gather2 + relu/bias + fc -> out                    (128 nodes/block)
    gather_fc_kernel<<<(n + 127) / 128, 256, 0, stream>>>(off, cnt, srow, g2, dinv, b2, fcW, fcb, out, n);
}

// Round 9
// 141.645 us; speedup vs baseline: 1.0460x; 1.0460x over previous
//
#include <hip/hip_runtime.h>
#include <hip/hip_fp16.h>

// GCN 2-layer forward. N=100000 nodes, E=1600000 directed edges.
// out[c] = relu( dinv[c] * ( sum_{r->c} g[r] + g[c] ) + b ),  g = (x@W)*dinv
// dinv = rsqrt(indeg+1) (self-loops folded in analytically).
// Round 19: revert to r17 structure (145.5us best) + two orthogonal trims:
//  (a) init kernel deleted: bcursor is a RELATIVE counter zeroed by
//      hipMemsetAsync; fill computes absolute run start as b*CAP+rel; sort
//      reads m = bcursor[b] directly; sentinel-row zeroing moved into sort
//      block 0. One serial launch removed.
//  (b) gather loops deepened to 8 edges in flight (padded CSR, branchless).
//      r18 proved gathers are latency-bound on random line requests
//      (32B-L2 rows == 64B-L3 rows in time), so per-thread MLP is the lever;
//      r18's 8-deep was confounded by halved wave count (2 lanes/node) —
//      here 8-deep rides on r17's 4-lane/64-node shape.
// Negative results bank (do NOT retry): LDS-atomic accumulation (r11/12);
// degree-ranked perm (r13); global counting scatter (r14: 17x write amp);
// 32KB col cache in fill / NBUCKET=782 (r15); gather-before-matmul /
// 2-lane gather1 (r18: row size & cache tier don't matter, wave count does).

constexpr int NN  = 100000;
constexpr int FIN = 16;
constexpr int FH  = 32;   // hidden
constexpr int FO  = 16;   // layer-2 out

constexpr int BK      = 256;                     // nodes per bucket (col>>8)
constexpr int NBUCKET = (NN + BK - 1) / BK;      // 391
constexpr int CHUNK   = 8192;                    // edges per block (fill)
constexpr int CAP     = 5632;                    // bucket capacity (mean 4092 + pad, +18 sigma)

static __device__ __forceinline__ int pack2(float a, float b) {
    __half2 t = __float22half2_rn(make_float2(a, b));
    return *reinterpret_cast<int*>(&t);
}
static __device__ __forceinline__ float2 unpack2(int v) {
    __half2 t = *reinterpret_cast<__half2*>(&v);
    return __half22float2(t);
}

// ---- phase A: bucket fill into fixed segments. Per-block run reservation.
// bcursor[b] is a RELATIVE cursor (memset to 0); absolute = b*CAP + rel. ----
__global__ __launch_bounds__(512) void bucket_fill_kernel(
        const int* __restrict__ row, const int* __restrict__ col,
        int* __restrict__ bcursor, int* __restrict__ srow, int E) {
    __shared__ int bcnt[NBUCKET];
    __shared__ int bcur[NBUCKET];
    int t = threadIdx.x;
    int e0 = blockIdx.x * CHUNK;
    int m = E - e0; if (m > CHUNK) m = CHUNK;
    for (int b = t; b < NBUCKET; b += 512) bcnt[b] = 0;
    __syncthreads();
    for (int i = t; i < m; i += 512)
        atomicAdd(&bcnt[col[e0 + i] >> 8], 1);
    __syncthreads();
    for (int b = t; b < NBUCKET; b += 512) {
        int v = bcnt[b];
        bcur[b] = v ? (b * CAP + atomicAdd(&bcursor[b], v)) : 0;  // absolute run start
    }
    __syncthreads();
    for (int i = t; i < m; i += 512) {
        int c = col[e0 + i];
        int r = row[e0 + i];
        int p = atomicAdd(&bcur[c >> 8], 1);
        srow[p] = ((c & (BK - 1)) << 17) | r;          // pack (c_local, r); r < 2^17
    }
}

// ---- phase B: per-bucket LDS counting sort; emits off/cnt/dinv AND g1 rows.
// 512 threads: sort phases use all; mm1 split by feature-half across t>>8.
// Offsets padded to multiples of 4; pad slots hold sentinel NN.
// Block 0 additionally zeroes the sentinel rows g1[NN], g2[NN].
__global__ __launch_bounds__(512) void bucket_sort_mm1_kernel(
        const int* __restrict__ bcursor, int* __restrict__ srow,
        int* __restrict__ off, int* __restrict__ cnt, float* __restrict__ dinv,
        const float* __restrict__ x, const float* __restrict__ W1,
        __half* __restrict__ g1, __half* __restrict__ g2, int n) {
    __shared__ int ebuf[CAP];
    __shared__ int sorted[CAP];
    __shared__ int cnt2[BK];
    __shared__ float sdi[BK];
    __shared__ int wsum[4];
    __shared__ int wbase[4];
    __shared__ int Mtot;
    __shared__ float w1[FIN * FH];
    int t = threadIdx.x;
    for (int i = t; i < FIN * FH; i += 512) w1[i] = W1[i];
    if (blockIdx.x == 0 && t < 6) {                    // sentinel rows = 0
        if (t < 4) ((int4*)(g1 + (long long)NN * FH))[t] = make_int4(0, 0, 0, 0);
        else       ((int4*)(g2 + (long long)NN * FO))[t - 4] = make_int4(0, 0, 0, 0);
    }
    int lo = blockIdx.x << 8;
    int nodes = n - lo; if (nodes > BK) nodes = BK;
    int s0 = blockIdx.x * CAP;
    int m = bcursor[blockIdx.x];                       // relative count == edges here
    if (m > CAP) m = CAP;                              // paranoia guard (never hit)
    if (m < 0)  m = 0;
    for (int i = t; i < m; i += 512) ebuf[i] = srow[s0 + i];
    if (t < BK) cnt2[t] = 0;
    __syncthreads();
    for (int i = t; i < m; i += 512) atomicAdd(&cnt2[ebuf[i] >> 17], 1);
    __syncthreads();
    int v = 0, pv = 0, s = 0, excl = 0;
    if (t < BK) {
        v  = cnt2[t];
        pv = (v + 3) & ~3;                             // padded count
        s  = pv;
        #pragma unroll
        for (int d = 1; d < 64; d <<= 1) {             // inclusive wave scan
            int u = __shfl_up(s, d, 64);
            if ((t & 63) >= d) s += u;
        }
        if ((t & 63) == 63) wsum[t >> 6] = s;
    }
    __syncthreads();
    if (t < 4) {
        int b = 0;
        for (int k = 0; k < t; k++) b += wsum[k];
        wbase[t] = b;
    }
    __syncthreads();
    if (t < BK) {
        excl = s + wbase[t >> 6] - pv;                 // exclusive padded prefix
        cnt2[t] = excl;                                // cursor for scatter
        float di = rsqrtf((float)v + 1.0f);
        sdi[t] = di;
        if (t < nodes) {
            off[lo + t]  = s0 + excl;
            cnt[lo + t]  = v;
            dinv[lo + t] = di;
        }
        if (t == BK - 1) Mtot = excl + pv;             // total padded length
    }
    __syncthreads();
    for (int i = t; i < m; i += 512) {
        int pvv = ebuf[i];
        int p = atomicAdd(&cnt2[pvv >> 17], 1);
        sorted[p] = pvv & 0x1FFFF;
    }
    __syncthreads();
    if (t < BK) {                                      // sentinel pads
        for (int p = excl + v; p < excl + pv; p++) sorted[p] = NN;
    }
    __syncthreads();
    int M = Mtot; if (M > CAP) M = CAP;
    for (int i = t; i < M; i += 512) srow[s0 + i] = sorted[i];
    // ---- fused mm1 (split): lane=t>>8 computes feature-half of node t&255 ----
    int lane = t >> 8;                                 // 0 or 1
    int nd0  = t & 255;
    if (nd0 < nodes) {
        int nd = lo + nd0;
        float di = sdi[nd0];
        float xi[FIN];
        const float4* xv = (const float4*)(x + (long long)nd * FIN);
        #pragma unroll
        for (int i = 0; i < FIN / 4; i++) {
            float4 vv = xv[i];
            xi[4*i] = vv.x; xi[4*i+1] = vv.y; xi[4*i+2] = vv.z; xi[4*i+3] = vv.w;
        }
        float h[16];
        #pragma unroll
        for (int j = 0; j < 16; j++) h[j] = 0.f;
        const float* wl = w1 + lane * 16;
        #pragma unroll
        for (int i = 0; i < FIN; i++) {
            float xs = xi[i];
            #pragma unroll
            for (int j = 0; j < 16; j++) h[j] += xs * wl[i * FH + j];
        }
        int4* gv = (int4*)(g1 + (long long)nd * FH) + lane * 2;
        gv[0] = make_int4(pack2(h[0]*di,  h[1]*di),  pack2(h[2]*di,  h[3]*di),
                          pack2(h[4]*di,  h[5]*di),  pack2(h[6]*di,  h[7]*di));
        gv[1] = make_int4(pack2(h[8]*di,  h[9]*di),  pack2(h[10]*di, h[11]*di),
                          pack2(h[12]*di, h[13]*di), pack2(h[14]*di, h[15]*di));
    }
}

// ---- fused gather layer1 (fp16 rows) + relu/bias + mm2 + scale -> g2 (fp16) ----
// block = 256 threads = 64 nodes x 4 lanes (lane = 8 feats = int4 = 16 B).
// Padded CSR, 8 edges in flight.
constexpr int XS = 36;   // LDS stride: 16B-aligned writes, 2-way (free) reads
__global__ __launch_bounds__(256) void gather_mm2_kernel(
        const int* __restrict__ off, const int* __restrict__ cnt,
        const int* __restrict__ srow, const __half* __restrict__ g1,
        const float* __restrict__ dinv, const float* __restrict__ b1,
        const float* __restrict__ W2, __half* __restrict__ g2, int n) {
    __shared__ float xs[64 * XS];          // 64 nodes x 32 feats (stride 36)
    __shared__ float w[FH * FO];           // 32x16
    __shared__ float bb[FH];
    int t = threadIdx.x;
    for (int i = t; i < FH * FO; i += 256) w[i] = W2[i];
    if (t < FH) bb[t] = b1[t];
    int nl = t >> 2;                       // node-local 0..63
    int q = t & 3;                         // 8-feat group
    int node = blockIdx.x * 64 + nl;
    bool live = node < n;
    float acc[8] = {0.f,0.f,0.f,0.f,0.f,0.f,0.f,0.f};
    float di = 0.f;
    if (live) {
        di = dinv[node];
        {   // self-loop seed
            int4 raw = ((const int4*)(g1 + (long long)node * FH))[q];
            float2 f0 = unpack2(raw.x), f1 = unpack2(raw.y);
            float2 f2 = unpack2(raw.z), f3 = unpack2(raw.w);
            acc[0] = f0.x; acc[1] = f0.y; acc[2] = f1.x; acc[3] = f1.y;
            acc[4] = f2.x; acc[5] = f2.y; acc[6] = f3.x; acc[7] = f3.y;
        }
        int s = off[node];
        int m = cnt[node];
        int i = 0;
        for (; i + 7 < m; i += 8) {        // 8 rows in flight
            int4 ix0 = *(const int4*)(srow + s + i);
            int4 ix1 = *(const int4*)(srow + s + i + 4);
            int4 ra = ((const int4*)(g1 + (long long)ix0.x * FH))[q];
            int4 rb = ((const int4*)(g1 + (long long)ix0.y * FH))[q];
            int4 rc = ((const int4*)(g1 + (long long)ix0.z * FH))[q];
            int4 rd = ((const int4*)(g1 + (long long)ix0.w * FH))[q];
            int4 re = ((const int4*)(g1 + (long long)ix1.x * FH))[q];
            int4 rf = ((const int4*)(g1 + (long long)ix1.y * FH))[q];
            int4 rg = ((const int4*)(g1 + (long long)ix1.z * FH))[q];
            int4 rh = ((const int4*)(g1 + (long long)ix1.w * FH))[q];
            float2 u;
            u = unpack2(ra.x); acc[0] += u.x; acc[1] += u.y;
            u = unpack2(ra.y); acc[2] += u.x; acc[3] += u.y;
            u = unpack2(ra.z); acc[4] += u.x; acc[5] += u.y;
            u = unpack2(ra.w); acc[6] += u.x; acc[7] += u.y;
            u = unpack2(rb.x); acc[0] += u.x; acc[1] += u.y;
            u = unpack2(rb.y); acc[2] += u.x; acc[3] += u.y;
            u = unpack2(rb.z); acc[4] += u.x; acc[5] += u.y;
            u = unpack2(rb.w); acc[6] += u.x; acc[7] += u.y;
            u = unpack2(rc.x); acc[0] += u.x; acc[1] += u.y;
            u = unpack2(rc.y); acc[2] += u.x; acc[3] += u.y;
            u = unpack2(rc.z); acc[4] += u.x; acc[5] += u.y;
            u = unpack2(rc.w); acc[6] += u.x; acc[7] += u.y;
            u = unpack2(rd.x); acc[0] += u.x; acc[1] += u.y;
            u = unpack2(rd.y); acc[2] += u.x; acc[3] += u.y;
            u = unpack2(rd.z); acc[4] += u.x; acc[5] += u.y;
            u = unpack2(rd.w); acc[6] += u.x; acc[7] += u.y;
            u = unpack2(re.x); acc[0] += u.x; acc[1] += u.y;
            u = unpack2(re.y); acc[2] += u.x; acc[3] += u.y;
            u = unpack2(re.z); acc[4] += u.x; acc[5] += u.y;
            u = unpack2(re.w); acc[6] += u.x; acc[7] += u.y;
            u = unpack2(rf.x); acc[0] += u.x; acc[1] += u.y;
            u = unpack2(rf.y); acc[2] += u.x; acc[3] += u.y;
            u = unpack2(rf.z); acc[4] += u.x; acc[5] += u.y;
            u = unpack2(rf.w); acc[6] += u.x; acc[7] += u.y;
            u = unpack2(rg.x); acc[0] += u.x; acc[1] += u.y;
            u = unpack2(rg.y); acc[2] += u.x; acc[3] += u.y;
            u = unpack2(rg.z); acc[4] += u.x; acc[5] += u.y;
            u = unpack2(rg.w); acc[6] += u.x; acc[7] += u.y;
            u = unpack2(rh.x); acc[0] += u.x; acc[1] += u.y;
            u = unpack2(rh.y); acc[2] += u.x; acc[3] += u.y;
            u = unpack2(rh.z); acc[4] += u.x; acc[5] += u.y;
            u = unpack2(rh.w); acc[6] += u.x; acc[7] += u.y;
        }
        for (; i < m; i += 4) {            // remainder is 0 or 4 (padded)
            int4 ix = *(const int4*)(srow + s + i);
            int4 ra = ((const int4*)(g1 + (long long)ix.x * FH))[q];
            int4 rb = ((const int4*)(g1 + (long long)ix.y * FH))[q];
            int4 rc = ((const int4*)(g1 + (long long)ix.z * FH))[q];
            int4 rd = ((const int4*)(g1 + (long long)ix.w * FH))[q];
            float2 u;
            u = unpack2(ra.x); acc[0] += u.x; acc[1] += u.y;
            u = unpack2(ra.y); acc[2] += u.x; acc[3] += u.y;
            u = unpack2(ra.z); acc[4] += u.x; acc[5] += u.y;
            u = unpack2(ra.w); acc[6] += u.x; acc[7] += u.y;
            u = unpack2(rb.x); acc[0] += u.x; acc[1] += u.y;
            u = unpack2(rb.y); acc[2] += u.x; acc[3] += u.y;
            u = unpack2(rb.z); acc[4] += u.x; acc[5] += u.y;
            u = unpack2(rb.w); acc[6] += u.x; acc[7] += u.y;
            u = unpack2(rc.x); acc[0] += u.x; acc[1] += u.y;
            u = unpack2(rc.y); acc[2] += u.x; acc[3] += u.y;
            u = unpack2(rc.z); acc[4] += u.x; acc[5] += u.y;
            u = unpack2(rc.w); acc[6] += u.x; acc[7] += u.y;
            u = unpack2(rd.x); acc[0] += u.x; acc[1] += u.y;
            u = unpack2(rd.y); acc[2] += u.x; acc[3] += u.y;
            u = unpack2(rd.z); acc[4] += u.x; acc[5] += u.y;
            u = unpack2(rd.w); acc[6] += u.x; acc[7] += u.y;
        }
    }
    __syncthreads();                       // w/bb loaded; also before xs write
    if (live) {
        // x1[8q..8q+7] = relu(acc*di + b1)
        float* xr = xs + nl * XS + 8 * q;
        #pragma unroll
        for (int j = 0; j < 8; j++) {
            float a = acc[j] * di + bb[8*q + j];
            xr[j] = a > 0.f ? a : 0.f;
        }
    }
    __syncthreads();
    if (live) {
        // lane q computes outputs k = 4q..4q+3 of x1 @ W2 (FO=16)
        const float* xr = xs + nl * XS;
        int k0 = 4 * q;
        float o0 = 0.f, o1 = 0.f, o2 = 0.f, o3 = 0.f;
        #pragma unroll
        for (int j = 0; j < FH; j++) {
            float xj = xr[j];
            const float* wr = w + j * FO + k0;
            o0 += xj * wr[0];
            o1 += xj * wr[1];
            o2 += xj * wr[2];
            o3 += xj * wr[3];
        }
        ((int2*)(g2 + (long long)node * FO))[q] =
            make_int2(pack2(o0 * di, o1 * di), pack2(o2 * di, o3 * di));
    }
}

// ---- fused gather layer2 (fp16 rows) + relu/bias + fc -> out ----
// block = 256 threads = 128 nodes x 2 lanes; padded CSR, 8 edges in flight.
__global__ __launch_bounds__(256) void gather_fc_kernel(
        const int* __restrict__ off, const int* __restrict__ cnt,
        const int* __restrict__ srow, const __half* __restrict__ g2,
        const float* __restrict__ dinv, const float* __restrict__ b2,
        const float* __restrict__ fcW, const float* __restrict__ fcb,
        float* __restrict__ out, int n) {
    __shared__ float w[FO];
    __shared__ float bb[FO];
    __shared__ float fb;
    int t = threadIdx.x;
    if (t < FO) { w[t] = fcW[t]; bb[t] = b2[t]; }
    if (t == 0) fb = fcb[0];
    __syncthreads();
    int node = blockIdx.x * 128 + (t >> 1);
    int q = t & 1;
    if (node >= n) return;
    float di = dinv[node];
    float acc[8];
    {   // self-loop seed
        int4 raw = ((const int4*)(g2 + (long long)node * FO))[q];
        float2 f0 = unpack2(raw.x), f1 = unpack2(raw.y);
        float2 f2 = unpack2(raw.z), f3 = unpack2(raw.w);
        acc[0] = f0.x; acc[1] = f0.y; acc[2] = f1.x; acc[3] = f1.y;
        acc[4] = f2.x; acc[5] = f2.y; acc[6] = f3.x; acc[7] = f3.y;
    }
    int s = off[node];
    int m = cnt[node];
    int i = 0;
    for (; i + 7 < m; i += 8) {            // 8 rows in flight
        int4 ix0 = *(const int4*)(srow + s + i);
        int4 ix1 = *(const int4*)(srow + s + i + 4);
        int4 ra = ((const int4*)(g2 + (long long)ix0.x * FO))[q];
        int4 rb = ((const int4*)(g2 + (long long)ix0.y * FO))[q];
        int4 rc = ((const int4*)(g2 + (long long)ix0.z * FO))[q];
        int4 rd = ((const int4*)(g2 + (long long)ix0.w * FO))[q];
        int4 re = ((const int4*)(g2 + (long long)ix1.x * FO))[q];
        int4 rf = ((const int4*)(g2 + (long long)ix1.y * FO))[q];
        int4 rg = ((const int4*)(g2 + (long long)ix1.z * FO))[q];
        int4 rh = ((const int4*)(g2 + (long long)ix1.w * FO))[q];
        float2 u;
        u = unpack2(ra.x); acc[0] += u.x; acc[1] += u.y;
        u = unpack2(ra.y); acc[2] += u.x; acc[3] += u.y;
        u = unpack2(ra.z); acc[4] += u.x; acc[5] += u.y;
        u = unpack2(ra.w); acc[6] += u.x; acc[7] += u.y;
        u = unpack2(rb.x); acc[0] += u.x; acc[1] += u.y;
        u = unpack2(rb.y); acc[2] += u.x; acc[3] += u.y;
        u = unpack2(rb.z); acc[4] += u.x; acc[5] += u.y;
        u = unpack2(rb.w); acc[6] += u.x; acc[7] += u.y;
        u = unpack2(rc.x); acc[0] += u.x; acc[1] += u.y;
        u = unpack2(rc.y); acc[2] += u.x; acc[3] += u.y;
        u = unpack2(rc.z); acc[4] += u.x; acc[5] += u.y;
        u = unpack2(rc.w); acc[6] += u.x; acc[7] += u.y;
        u = unpack2(rd.x); acc[0] += u.x; acc[1] += u.y;
        u = unpack2(rd.y); acc[2] += u.x; acc[3] += u.y;
        u = unpack2(rd.z); acc[4] += u.x; acc[5] += u.y;
        u = unpack2(rd.w); acc[6] += u.x; acc[7] += u.y;
        u = unpack2(re.x); acc[0] += u.x; acc[1] += u.y;
        u = unpack2(re.y); acc[2] += u.x; acc[3] += u.y;
        u = unpack2(re.z); acc[4] += u.x; acc[5] += u.y;
        u = unpack2(re.w); acc[6] += u.x; acc[7] += u.y;
        u = unpack2(rf.x); acc[0] += u.x; acc[1] += u.y;
        u = unpack2(rf.y); acc[2] += u.x; acc[3] += u.y;
        u = unpack2(rf.z); acc[4] += u.x; acc[5] += u.y;
        u = unpack2(rf.w); acc[6] += u.x; acc[7] += u.y;
        u = unpack2(rg.x); acc[0] += u.x; acc[1] += u.y;
        u = unpack2(rg.y); acc[2] += u.x; acc[3] += u.y;
        u = unpack2(rg.z); acc[4] += u.x; acc[5] += u.y;
        u = unpack2(rg.w); acc[6] += u.x; acc[7] += u.y;
        u = unpack2(rh.x); acc[0] += u.x; acc[1] += u.y;
        u = unpack2(rh.y); acc[2] += u.x; acc[3] += u.y;
        u = unpack2(rh.z); acc[4] += u.x; acc[5] += u.y;
        u = unpack2(rh.w); acc[6] += u.x; acc[7] += u.y;
    }
    for (; i < m; i += 4) {                // remainder is 0 or 4 (padded)
        int4 ix = *(const int4*)(srow + s + i);
        int4 ra = ((const int4*)(g2 + (long long)ix.x * FO))[q];
        int4 rb = ((const int4*)(g2 + (long long)ix.y * FO))[q];
        int4 rc = ((const int4*)(g2 + (long long)ix.z * FO))[q];
        int4 rd = ((const int4*)(g2 + (long long)ix.w * FO))[q];
        float2 u;
        u = unpack2(ra.x); acc[0] += u.x; acc[1] += u.y;
        u = unpack2(ra.y); acc[2] += u.x; acc[3] += u.y;
        u = unpack2(ra.z); acc[4] += u.x; acc[5] += u.y;
        u = unpack2(ra.w); acc[6] += u.x; acc[7] += u.y;
        u = unpack2(rb.x); acc[0] += u.x; acc[1] += u.y;
        u = unpack2(rb.y); acc[2] += u.x; acc[3] += u.y;
        u = unpack2(rb.z); acc[4] += u.x; acc[5] += u.y;
        u = unpack2(rb.w); acc[6] += u.x; acc[7] += u.y;
        u = unpack2(rc.x); acc[0] += u.x; acc[1] += u.y;
        u = unpack2(rc.y); acc[2] += u.x; acc[3] += u.y;
        u = unpack2(rc.z); acc[4] += u.x; acc[5] += u.y;
        u = unpack2(rc.w); acc[6] += u.x; acc[7] += u.y;
        u = unpack2(rd.x); acc[0] += u.x; acc[1] += u.y;
        u = unpack2(rd.y); acc[2] += u.x; acc[3] += u.y;
        u = unpack2(rd.z); acc[4] += u.x; acc[5] += u.y;
        u = unpack2(rd.w); acc[6] += u.x; acc[7] += u.y;
    }
    // x2 = relu(acc*di + b2[8q..]); partial dot with fcW
    float p = 0.f;
    #pragma unroll
    for (int j = 0; j < 8; j++) {
        float a = acc[j] * di + bb[8*q + j];
        p += (a > 0.f ? a : 0.f) * w[8*q + j];
    }
    p += __shfl_down(p, 1, 2);             // reduce the node's 2 lanes
    if (q == 0) out[node] = p + fb;
}

extern "C" void kernel_launch(void* const* d_in, const int* in_sizes, int n_in,
                              void* d_out, int out_size, void* d_ws, size_t ws_size,
                              hipStream_t stream) {
    const int*   edge = (const int*)d_in[0];        // [2, E] int32
    const float* x    = (const float*)d_in[1];      // [N, 16]
    const float* W1   = (const float*)d_in[2];      // [16, 32]
    const float* b1   = (const float*)d_in[3];      // [32]
    const float* W2   = (const float*)d_in[4];      // [32, 16]
    const float* b2   = (const float*)d_in[5];      // [16]
    const float* fcW  = (const float*)d_in[6];      // [16, 1]
    const float* fcb  = (const float*)d_in[7];      // [1]
    float* out = (float*)d_out;

    const int E = in_sizes[0] / 2;                  // 1600000
    const int n = NN;
    const int* row = edge;
    const int* col = edge + E;

    // workspace layout (4-byte units), regions 128-elem aligned:
    const size_t nA = (size_t)((n + 127) & ~127);
    char* wsb = (char*)d_ws;
    int*   cnt     = (int*)wsb;                     // n ints (per-node degree)
    int*   off     = cnt + nA;                      // n ints (padded CSR offsets)
    float* dinv    = (float*)(off + nA);            // n floats
    int*   bcursor = (int*)(dinv + nA);             // NBUCKET ints (pad 512)
    int*   srow    = bcursor + 512;                 // (NBUCKET+1)*CAP ints (+slack seg)
    int*   srowEnd = srow + (size_t)(NBUCKET + 1) * CAP;
    __half* g1     = (__half*)srowEnd;              // (n+1)*FH halfs (sentinel row at NN)
    __half* g2     = g1 + (size_t)(n + 1) * FH;     // (n+1)*FO halfs (sentinel row at NN)

    const int nChunkBlocks = (E + CHUNK - 1) / CHUNK;   // 196

    // 1. bcursor = 0 (relative cursors)
    hipMemsetAsync(bcursor, 0, 512 * sizeof(int), stream);
    // 2. phase A: bucket fill into fixed segments; per-block run reservation
    bucket_fill_kernel<<<nChunkBlocks, 512, 0, stream>>>(row, col, bcursor, srow, E);
    // 3. phase B: per-bucket LDS counting sort (padded offsets) + sentinels + mm1
    bucket_sort_mm1_kernel<<<NBUCKET, 512, 0, stream>>>(bcursor, srow, off, cnt, dinv, x, W1, g1, g2, n);
    // 4. fused gather1 + relu/bias + mm2 + scale -> g2   (64 nodes/block, 8-deep)
    gather_mm2_kernel<<<(n + 63) / 64, 256, 0, stream>>>(off, cnt, srow, g1, dinv, b1, W2, g2, n);
    // 5. fused gather2 + relu/bias + fc -> out            (128 nodes/block, 8-deep)
    gather_fc_kernel<<<(n + 127) / 128, 256, 0, stream>>>(off, cnt, srow, g2, dinv, b2, fcW, fcb, out, n);
}

// Round 10
// 139.465 us; speedup vs baseline: 1.0623x; 1.0156x over previous
//
#include <hip/hip_runtime.h>
#include <hip/hip_fp16.h>

// GCN 2-layer forward. N=100000 nodes, E=1600000 directed edges.
// out[c] = relu( dinv[c] * ( sum_{r->c} g[r] + g[c] ) + b ),  g = (x@W)*dinv
// dinv = rsqrt(indeg+1) (self-loops folded in analytically).
// Round 20: occupancy bump for the two preprocessing kernels (the gathers
// are at their measured random-line-request wall; r13/r18 nulls).
//  (a) fill at 1024 threads: was 196 blocks x 8 waves = 19% occupancy with
//      60 idle CUs; now 16 waves/block. Memory pattern unchanged.
//  (b) sort at 1024 threads: 391 blocks x 16 waves ~= 76% occupancy (LDS
//      ~50KB -> 2 blocks/CU). Wave-scan untouched (t<256); fused mm1 split
//      4-ways by feature-quarter (each lane writes one int4).
// Negative results bank (do NOT retry): LDS-atomic accumulation (r11/12);
// degree-ranked perm (r13); global counting scatter (r14: 17x write amp);
// 32KB col cache in fill / NBUCKET=782 (r15); gather-before-matmul /
// 2-lane gather1 (r18: row size & cache tier don't matter, wave count does).

constexpr int NN  = 100000;
constexpr int FIN = 16;
constexpr int FH  = 32;   // hidden
constexpr int FO  = 16;   // layer-2 out

constexpr int BK      = 256;                     // nodes per bucket (col>>8)
constexpr int NBUCKET = (NN + BK - 1) / BK;      // 391
constexpr int CHUNK   = 8192;                    // edges per block (fill)
constexpr int CAP     = 5632;                    // bucket capacity (mean 4092 + pad, +18 sigma)

static __device__ __forceinline__ int pack2(float a, float b) {
    __half2 t = __float22half2_rn(make_float2(a, b));
    return *reinterpret_cast<int*>(&t);
}
static __device__ __forceinline__ float2 unpack2(int v) {
    __half2 t = *reinterpret_cast<__half2*>(&v);
    return __half22float2(t);
}

// ---- phase A: bucket fill into fixed segments. Per-block run reservation.
// bcursor[b] is a RELATIVE cursor (memset to 0); absolute = b*CAP + rel. ----
__global__ __launch_bounds__(1024) void bucket_fill_kernel(
        const int* __restrict__ row, const int* __restrict__ col,
        int* __restrict__ bcursor, int* __restrict__ srow, int E) {
    __shared__ int bcnt[NBUCKET];
    __shared__ int bcur[NBUCKET];
    int t = threadIdx.x;
    int e0 = blockIdx.x * CHUNK;
    int m = E - e0; if (m > CHUNK) m = CHUNK;
    for (int b = t; b < NBUCKET; b += 1024) bcnt[b] = 0;
    __syncthreads();
    for (int i = t; i < m; i += 1024)
        atomicAdd(&bcnt[col[e0 + i] >> 8], 1);
    __syncthreads();
    for (int b = t; b < NBUCKET; b += 1024) {
        int v = bcnt[b];
        bcur[b] = v ? (b * CAP + atomicAdd(&bcursor[b], v)) : 0;  // absolute run start
    }
    __syncthreads();
    for (int i = t; i < m; i += 1024) {
        int c = col[e0 + i];
        int r = row[e0 + i];
        int p = atomicAdd(&bcur[c >> 8], 1);
        srow[p] = ((c & (BK - 1)) << 17) | r;          // pack (c_local, r); r < 2^17
    }
}

// ---- phase B: per-bucket LDS counting sort; emits off/cnt/dinv AND g1 rows.
// 1024 threads: sort phases use all; mm1 split by feature-quarter (t>>8).
// Offsets padded to multiples of 4; pad slots hold sentinel NN.
// Block 0 additionally zeroes the sentinel rows g1[NN], g2[NN].
__global__ __launch_bounds__(1024) void bucket_sort_mm1_kernel(
        const int* __restrict__ bcursor, int* __restrict__ srow,
        int* __restrict__ off, int* __restrict__ cnt, float* __restrict__ dinv,
        const float* __restrict__ x, const float* __restrict__ W1,
        __half* __restrict__ g1, __half* __restrict__ g2, int n) {
    __shared__ int ebuf[CAP];
    __shared__ int sorted[CAP];
    __shared__ int cnt2[BK];
    __shared__ float sdi[BK];
    __shared__ int wsum[4];
    __shared__ int wbase[4];
    __shared__ int Mtot;
    __shared__ float w1[FIN * FH];
    int t = threadIdx.x;
    for (int i = t; i < FIN * FH; i += 1024) w1[i] = W1[i];
    if (blockIdx.x == 0 && t < 6) {                    // sentinel rows = 0
        if (t < 4) ((int4*)(g1 + (long long)NN * FH))[t] = make_int4(0, 0, 0, 0);
        else       ((int4*)(g2 + (long long)NN * FO))[t - 4] = make_int4(0, 0, 0, 0);
    }
    int lo = blockIdx.x << 8;
    int nodes = n - lo; if (nodes > BK) nodes = BK;
    int s0 = blockIdx.x * CAP;
    int m = bcursor[blockIdx.x];                       // relative count == edges here
    if (m > CAP) m = CAP;                              // paranoia guard (never hit)
    if (m < 0)  m = 0;
    for (int i = t; i < m; i += 1024) ebuf[i] = srow[s0 + i];
    if (t < BK) cnt2[t] = 0;
    __syncthreads();
    for (int i = t; i < m; i += 1024) atomicAdd(&cnt2[ebuf[i] >> 17], 1);
    __syncthreads();
    int v = 0, pv = 0, s = 0, excl = 0;
    if (t < BK) {
        v  = cnt2[t];
        pv = (v + 3) & ~3;                             // padded count
        s  = pv;
        #pragma unroll
        for (int d = 1; d < 64; d <<= 1) {             // inclusive wave scan
            int u = __shfl_up(s, d, 64);
            if ((t & 63) >= d) s += u;
        }
        if ((t & 63) == 63) wsum[t >> 6] = s;
    }
    __syncthreads();
    if (t < 4) {
        int b = 0;
        for (int k = 0; k < t; k++) b += wsum[k];
        wbase[t] = b;
    }
    __syncthreads();
    if (t < BK) {
        excl = s + wbase[t >> 6] - pv;                 // exclusive padded prefix
        cnt2[t] = excl;                                // cursor for scatter
        float di = rsqrtf((float)v + 1.0f);
        sdi[t] = di;
        if (t < nodes) {
            off[lo + t]  = s0 + excl;
            cnt[lo + t]  = v;
            dinv[lo + t] = di;
        }
        if (t == BK - 1) Mtot = excl + pv;             // total padded length
    }
    __syncthreads();
    for (int i = t; i < m; i += 1024) {
        int pvv = ebuf[i];
        int p = atomicAdd(&cnt2[pvv >> 17], 1);
        sorted[p] = pvv & 0x1FFFF;
    }
    __syncthreads();
    if (t < BK) {                                      // sentinel pads
        for (int p = excl + v; p < excl + pv; p++) sorted[p] = NN;
    }
    __syncthreads();
    int M = Mtot; if (M > CAP) M = CAP;
    for (int i = t; i < M; i += 1024) srow[s0 + i] = sorted[i];
    // ---- fused mm1 (split): lane=t>>8 computes feature-quarter of node t&255 ----
    int lane = t >> 8;                                 // 0..3
    int nd0  = t & 255;
    if (nd0 < nodes) {
        int nd = lo + nd0;
        float di = sdi[nd0];
        float xi[FIN];
        const float4* xv = (const float4*)(x + (long long)nd * FIN);
        #pragma unroll
        for (int i = 0; i < FIN / 4; i++) {
            float4 vv = xv[i];
            xi[4*i] = vv.x; xi[4*i+1] = vv.y; xi[4*i+2] = vv.z; xi[4*i+3] = vv.w;
        }
        float h[8];
        #pragma unroll
        for (int j = 0; j < 8; j++) h[j] = 0.f;
        const float* wl = w1 + lane * 8;
        #pragma unroll
        for (int i = 0; i < FIN; i++) {
            float xs = xi[i];
            #pragma unroll
            for (int j = 0; j < 8; j++) h[j] += xs * wl[i * FH + j];
        }
        ((int4*)(g1 + (long long)nd * FH))[lane] =
            make_int4(pack2(h[0]*di, h[1]*di), pack2(h[2]*di, h[3]*di),
                      pack2(h[4]*di, h[5]*di), pack2(h[6]*di, h[7]*di));
    }
}

// ---- fused gather layer1 (fp16 rows) + relu/bias + mm2 + scale -> g2 (fp16) ----
// block = 256 threads = 64 nodes x 4 lanes (lane = 8 feats = int4 = 16 B).
// Padded CSR, 8 edges in flight.
constexpr int XS = 36;   // LDS stride: 16B-aligned writes, 2-way (free) reads
__global__ __launch_bounds__(256) void gather_mm2_kernel(
        const int* __restrict__ off, const int* __restrict__ cnt,
        const int* __restrict__ srow, const __half* __restrict__ g1,
        const float* __restrict__ dinv, const float* __restrict__ b1,
        const float* __restrict__ W2, __half* __restrict__ g2, int n) {
    __shared__ float xs[64 * XS];          // 64 nodes x 32 feats (stride 36)
    __shared__ float w[FH * FO];           // 32x16
    __shared__ float bb[FH];
    int t = threadIdx.x;
    for (int i = t; i < FH * FO; i += 256) w[i] = W2[i];
    if (t < FH) bb[t] = b1[t];
    int nl = t >> 2;                       // node-local 0..63
    int q = t & 3;                         // 8-feat group
    int node = blockIdx.x * 64 + nl;
    bool live = node < n;
    float acc[8] = {0.f,0.f,0.f,0.f,0.f,0.f,0.f,0.f};
    float di = 0.f;
    if (live) {
        di = dinv[node];
        {   // self-loop seed
            int4 raw = ((const int4*)(g1 + (long long)node * FH))[q];
            float2 f0 = unpack2(raw.x), f1 = unpack2(raw.y);
            float2 f2 = unpack2(raw.z), f3 = unpack2(raw.w);
            acc[0] = f0.x; acc[1] = f0.y; acc[2] = f1.x; acc[3] = f1.y;
            acc[4] = f2.x; acc[5] = f2.y; acc[6] = f3.x; acc[7] = f3.y;
        }
        int s = off[node];
        int m = cnt[node];
        int i = 0;
        for (; i + 7 < m; i += 8) {        // 8 rows in flight
            int4 ix0 = *(const int4*)(srow + s + i);
            int4 ix1 = *(const int4*)(srow + s + i + 4);
            int4 ra = ((const int4*)(g1 + (long long)ix0.x * FH))[q];
            int4 rb = ((const int4*)(g1 + (long long)ix0.y * FH))[q];
            int4 rc = ((const int4*)(g1 + (long long)ix0.z * FH))[q];
            int4 rd = ((const int4*)(g1 + (long long)ix0.w * FH))[q];
            int4 re = ((const int4*)(g1 + (long long)ix1.x * FH))[q];
            int4 rf = ((const int4*)(g1 + (long long)ix1.y * FH))[q];
            int4 rg = ((const int4*)(g1 + (long long)ix1.z * FH))[q];
            int4 rh = ((const int4*)(g1 + (long long)ix1.w * FH))[q];
            float2 u;
            u = unpack2(ra.x); acc[0] += u.x; acc[1] += u.y;
            u = unpack2(ra.y); acc[2] += u.x; acc[3] += u.y;
            u = unpack2(ra.z); acc[4] += u.x; acc[5] += u.y;
            u = unpack2(ra.w); acc[6] += u.x; acc[7] += u.y;
            u = unpack2(rb.x); acc[0] += u.x; acc[1] += u.y;
            u = unpack2(rb.y); acc[2] += u.x; acc[3] += u.y;
            u = unpack2(rb.z); acc[4] += u.x; acc[5] += u.y;
            u = unpack2(rb.w); acc[6] += u.x; acc[7] += u.y;
            u = unpack2(rc.x); acc[0] += u.x; acc[1] += u.y;
            u = unpack2(rc.y); acc[2] += u.x; acc[3] += u.y;
            u = unpack2(rc.z); acc[4] += u.x; acc[5] += u.y;
            u = unpack2(rc.w); acc[6] += u.x; acc[7] += u.y;
            u = unpack2(rd.x); acc[0] += u.x; acc[1] += u.y;
            u = unpack2(rd.y); acc[2] += u.x; acc[3] += u.y;
            u = unpack2(rd.z); acc[4] += u.x; acc[5] += u.y;
            u = unpack2(rd.w); acc[6] += u.x; acc[7] += u.y;
            u = unpack2(re.x); acc[0] += u.x; acc[1] += u.y;
            u = unpack2(re.y); acc[2] += u.x; acc[3] += u.y;
            u = unpack2(re.z); acc[4] += u.x; acc[5] += u.y;
            u = unpack2(re.w); acc[6] += u.x; acc[7] += u.y;
            u = unpack2(rf.x); acc[0] += u.x; acc[1] += u.y;
            u = unpack2(rf.y); acc[2] += u.x; acc[3] += u.y;
            u = unpack2(rf.z); acc[4] += u.x; acc[5] += u.y;
            u = unpack2(rf.w); acc[6] += u.x; acc[7] += u.y;
            u = unpack2(rg.x); acc[0] += u.x; acc[1] += u.y;
            u = unpack2(rg.y); acc[2] += u.x; acc[3] += u.y;
            u = unpack2(rg.z); acc[4] += u.x; acc[5] += u.y;
            u = unpack2(rg.w); acc[6] += u.x; acc[7] += u.y;
            u = unpack2(rh.x); acc[0] += u.x; acc[1] += u.y;
            u = unpack2(rh.y); acc[2] += u.x; acc[3] += u.y;
            u = unpack2(rh.z); acc[4] += u.x; acc[5] += u.y;
            u = unpack2(rh.w); acc[6] += u.x; acc[7] += u.y;
        }
        for (; i < m; i += 4) {            // remainder is 0 or 4 (padded)
            int4 ix = *(const int4*)(srow + s + i);
            int4 ra = ((const int4*)(g1 + (long long)ix.x * FH))[q];
            int4 rb = ((const int4*)(g1 + (long long)ix.y * FH))[q];
            int4 rc = ((const int4*)(g1 + (long long)ix.z * FH))[q];
            int4 rd = ((const int4*)(g1 + (long long)ix.w * FH))[q];
            float2 u;
            u = unpack2(ra.x); acc[0] += u.x; acc[1] += u.y;
            u = unpack2(ra.y); acc[2] += u.x; acc[3] += u.y;
            u = unpack2(ra.z); acc[4] += u.x; acc[5] += u.y;
            u = unpack2(ra.w); acc[6] += u.x; acc[7] += u.y;
            u = unpack2(rb.x); acc[0] += u.x; acc[1] += u.y;
            u = unpack2(rb.y); acc[2] += u.x; acc[3] += u.y;
            u = unpack2(rb.z); acc[4] += u.x; acc[5] += u.y;
            u = unpack2(rb.w); acc[6] += u.x; acc[7] += u.y;
            u = unpack2(rc.x); acc[0] += u.x; acc[1] += u.y;
            u = unpack2(rc.y); acc[2] += u.x; acc[3] += u.y;
            u = unpack2(rc.z); acc[4] += u.x; acc[5] += u.y;
            u = unpack2(rc.w); acc[6] += u.x; acc[7] += u.y;
            u = unpack2(rd.x); acc[0] += u.x; acc[1] += u.y;
            u = unpack2(rd.y); acc[2] += u.x; acc[3] += u.y;
            u = unpack2(rd.z); acc[4] += u.x; acc[5] += u.y;
            u = unpack2(rd.w); acc[6] += u.x; acc[7] += u.y;
        }
    }
    __syncthreads();                       // w/bb loaded; also before xs write
    if (live) {
        // x1[8q..8q+7] = relu(acc*di + b1)
        float* xr = xs + nl * XS + 8 * q;
        #pragma unroll
        for (int j = 0; j < 8; j++) {
            float a = acc[j] * di + bb[8*q + j];
            xr[j] = a > 0.f ? a : 0.f;
        }
    }
    __syncthreads();
    if (live) {
        // lane q computes outputs k = 4q..4q+3 of x1 @ W2 (FO=16)
        const float* xr = xs + nl * XS;
        int k0 = 4 * q;
        float o0 = 0.f, o1 = 0.f, o2 = 0.f, o3 = 0.f;
        #pragma unroll
        for (int j = 0; j < FH; j++) {
            float xj = xr[j];
            const float* wr = w + j * FO + k0;
            o0 += xj * wr[0];
            o1 += xj * wr[1];
            o2 += xj * wr[2];
            o3 += xj * wr[3];
        }
        ((int2*)(g2 + (long long)node * FO))[q] =
            make_int2(pack2(o0 * di, o1 * di), pack2(o2 * di, o3 * di));
    }
}

// ---- fused gather layer2 (fp16 rows) + relu/bias + fc -> out ----
// block = 256 threads = 128 nodes x 2 lanes; padded CSR, 8 edges in flight.
__global__ __launch_bounds__(256) void gather_fc_kernel(
        const int* __restrict__ off, const int* __restrict__ cnt,
        const int* __restrict__ srow, const __half* __restrict__ g2,
        const float* __restrict__ dinv, const float* __restrict__ b2,
        const float* __restrict__ fcW, const float* __restrict__ fcb,
        float* __restrict__ out, int n) {
    __shared__ float w[FO];
    __shared__ float bb[FO];
    __shared__ float fb;
    int t = threadIdx.x;
    if (t < FO) { w[t] = fcW[t]; bb[t] = b2[t]; }
    if (t == 0) fb = fcb[0];
    __syncthreads();
    int node = blockIdx.x * 128 + (t >> 1);
    int q = t & 1;
    if (node >= n) return;
    float di = dinv[node];
    float acc[8];
    {   // self-loop seed
        int4 raw = ((const int4*)(g2 + (long long)node * FO))[q];
        float2 f0 = unpack2(raw.x), f1 = unpack2(raw.y);
        float2 f2 = unpack2(raw.z), f3 = unpack2(raw.w);
        acc[0] = f0.x; acc[1] = f0.y; acc[2] = f1.x; acc[3] = f1.y;
        acc[4] = f2.x; acc[5] = f2.y; acc[6] = f3.x; acc[7] = f3.y;
    }
    int s = off[node];
    int m = cnt[node];
    int i = 0;
    for (; i + 7 < m; i += 8) {            // 8 rows in flight
        int4 ix0 = *(const int4*)(srow + s + i);
        int4 ix1 = *(const int4*)(srow + s + i + 4);
        int4 ra = ((const int4*)(g2 + (long long)ix0.x * FO))[q];
        int4 rb = ((const int4*)(g2 + (long long)ix0.y * FO))[q];
        int4 rc = ((const int4*)(g2 + (long long)ix0.z * FO))[q];
        int4 rd = ((const int4*)(g2 + (long long)ix0.w * FO))[q];
        int4 re = ((const int4*)(g2 + (long long)ix1.x * FO))[q];
        int4 rf = ((const int4*)(g2 + (long long)ix1.y * FO))[q];
        int4 rg = ((const int4*)(g2 + (long long)ix1.z * FO))[q];
        int4 rh = ((const int4*)(g2 + (long long)ix1.w * FO))[q];
        float2 u;
        u = unpack2(ra.x); acc[0] += u.x; acc[1] += u.y;
        u = unpack2(ra.y); acc[2] += u.x; acc[3] += u.y;
        u = unpack2(ra.z); acc[4] += u.x; acc[5] += u.y;
        u = unpack2(ra.w); acc[6] += u.x; acc[7] += u.y;
        u = unpack2(rb.x); acc[0] += u.x; acc[1] += u.y;
        u = unpack2(rb.y); acc[2] += u.x; acc[3] += u.y;
        u = unpack2(rb.z); acc[4] += u.x; acc[5] += u.y;
        u = unpack2(rb.w); acc[6] += u.x; acc[7] += u.y;
        u = unpack2(rc.x); acc[0] += u.x; acc[1] += u.y;
        u = unpack2(rc.y); acc[2] += u.x; acc[3] += u.y;
        u = unpack2(rc.z); acc[4] += u.x; acc[5] += u.y;
        u = unpack2(rc.w); acc[6] += u.x; acc[7] += u.y;
        u = unpack2(rd.x); acc[0] += u.x; acc[1] += u.y;
        u = unpack2(rd.y); acc[2] += u.x; acc[3] += u.y;
        u = unpack2(rd.z); acc[4] += u.x; acc[5] += u.y;
        u = unpack2(rd.w); acc[6] += u.x; acc[7] += u.y;
        u = unpack2(re.x); acc[0] += u.x; acc[1] += u.y;
        u = unpack2(re.y); acc[2] += u.x; acc[3] += u.y;
        u = unpack2(re.z); acc[4] += u.x; acc[5] += u.y;
        u = unpack2(re.w); acc[6] += u.x; acc[7] += u.y;
        u = unpack2(rf.x); acc[0] += u.x; acc[1] += u.y;
        u = unpack2(rf.y); acc[2] += u.x; acc[3] += u.y;
        u = unpack2(rf.z); acc[4] += u.x; acc[5] += u.y;
        u = unpack2(rf.w); acc[6] += u.x; acc[7] += u.y;
        u = unpack2(rg.x); acc[0] += u.x; acc[1] += u.y;
        u = unpack2(rg.y); acc[2] += u.x; acc[3] += u.y;
        u = unpack2(rg.z); acc[4] += u.x; acc[5] += u.y;
        u = unpack2(rg.w); acc[6] += u.x; acc[7] += u.y;
        u = unpack2(rh.x); acc[0] += u.x; acc[1] += u.y;
        u = unpack2(rh.y); acc[2] += u.x; acc[3] += u.y;
        u = unpack2(rh.z); acc[4] += u.x; acc[5] += u.y;
        u = unpack2(rh.w); acc[6] += u.x; acc[7] += u.y;
    }
    for (; i < m; i += 4) {                // remainder is 0 or 4 (padded)
        int4 ix = *(const int4*)(srow + s + i);
        int4 ra = ((const int4*)(g2 + (long long)ix.x * FO))[q];
        int4 rb = ((const int4*)(g2 + (long long)ix.y * FO))[q];
        int4 rc = ((const int4*)(g2 + (long long)ix.z * FO))[q];
        int4 rd = ((const int4*)(g2 + (long long)ix.w * FO))[q];
        float2 u;
        u = unpack2(ra.x); acc[0] += u.x; acc[1] += u.y;
        u = unpack2(ra.y); acc[2] += u.x; acc[3] += u.y;
        u = unpack2(ra.z); acc[4] += u.x; acc[5] += u.y;
        u = unpack2(ra.w); acc[6] += u.x; acc[7] += u.y;
        u = unpack2(rb.x); acc[0] += u.x; acc[1] += u.y;
        u = unpack2(rb.y); acc[2] += u.x; acc[3] += u.y;
        u = unpack2(rb.z); acc[4] += u.x; acc[5] += u.y;
        u = unpack2(rb.w); acc[6] += u.x; acc[7] += u.y;
        u = unpack2(rc.x); acc[0] += u.x; acc[1] += u.y;
        u = unpack2(rc.y); acc[2] += u.x; acc[3] += u.y;
        u = unpack2(rc.z); acc[4] += u.x; acc[5] += u.y;
        u = unpack2(rc.w); acc[6] += u.x; acc[7] += u.y;
        u = unpack2(rd.x); acc[0] += u.x; acc[1] += u.y;
        u = unpack2(rd.y); acc[2] += u.x; acc[3] += u.y;
        u = unpack2(rd.z); acc[4] += u.x; acc[5] += u.y;
        u = unpack2(rd.w); acc[6] += u.x; acc[7] += u.y;
    }
    // x2 = relu(acc*di + b2[8q..]); partial dot with fcW
    float p = 0.f;
    #pragma unroll
    for (int j = 0; j < 8; j++) {
        float a = acc[j] * di + bb[8*q + j];
        p += (a > 0.f ? a : 0.f) * w[8*q + j];
    }
    p += __shfl_down(p, 1, 2);             // reduce the node's 2 lanes
    if (q == 0) out[node] = p + fb;
}

extern "C" void kernel_launch(void* const* d_in, const int* in_sizes, int n_in,
                              void* d_out, int out_size, void* d_ws, size_t ws_size,
                              hipStream_t stream) {
    const int*   edge = (const int*)d_in[0];        // [2, E] int32
    const float* x    = (const float*)d_in[1];      // [N, 16]
    const float* W1   = (const float*)d_in[2];      // [16, 32]
    const float* b1   = (const float*)d_in[3];      // [32]
    const float* W2   = (const float*)d_in[4];      // [32, 16]
    const float* b2   = (const float*)d_in[5];      // [16]
    const float* fcW  = (const float*)d_in[6];      // [16, 1]
    const float* fcb  = (const float*)d_in[7];      // [1]
    float* out = (float*)d_out;

    const int E = in_sizes[0] / 2;                  // 1600000
    const int n = NN;
    const int* row = edge;
    const int* col = edge + E;

    // workspace layout (4-byte units), regions 128-elem aligned:
    const size_t nA = (size_t)((n + 127) & ~127);
    char* wsb = (char*)d_ws;
    int*   cnt     = (int*)wsb;                     // n ints (per-node degree)
    int*   off     = cnt + nA;                      // n ints (padded CSR offsets)
    float* dinv    = (float*)(off + nA);            // n floats
    int*   bcursor = (int*)(dinv + nA);             // NBUCKET ints (pad 512)
    int*   srow    = bcursor + 512;                 // (NBUCKET+1)*CAP ints (+slack seg)
    int*   srowEnd = srow + (size_t)(NBUCKET + 1) * CAP;
    __half* g1     = (__half*)srowEnd;              // (n+1)*FH halfs (sentinel row at NN)
    __half* g2     = g1 + (size_t)(n + 1) * FH;     // (n+1)*FO halfs (sentinel row at NN)

    const int nChunkBlocks = (E + CHUNK - 1) / CHUNK;   // 196

    // 1. bcursor = 0 (relative cursors)
    hipMemsetAsync(bcursor, 0, 512 * sizeof(int), stream);
    // 2. phase A: bucket fill into fixed segments; per-block run reservation
    bucket_fill_kernel<<<nChunkBlocks, 1024, 0, stream>>>(row, col, bcursor, srow, E);
    // 3. phase B: per-bucket LDS counting sort (padded offsets) + sentinels + mm1
    bucket_sort_mm1_kernel<<<NBUCKET, 1024, 0, stream>>>(bcursor, srow, off, cnt, dinv, x, W1, g1, g2, n);
    // 4. fused gather1 + relu/bias + mm2 + scale -> g2   (64 nodes/block, 8-deep)
    gather_mm2_kernel<<<(n + 63) / 64, 256, 0, stream>>>(off, cnt, srow, g1, dinv, b1, W2, g2, n);
    // 5. fused gather2 + relu/bias + fc -> out            (128 nodes/block, 8-deep)
    gather_fc_kernel<<<(n + 127) / 128, 256, 0, stream>>>(off, cnt, srow, g2, dinv, b2, fcW, fcb, out, n);
}

// Round 11
// 137.989 us; speedup vs baseline: 1.0737x; 1.0107x over previous
//
#include <hip/hip_runtime.h>
#include <hip/hip_fp16.h>

// GCN 2-layer forward. N=100000 nodes, E=1600000 directed edges.
// out[c] = relu( dinv[c] * ( sum_{r->c} g[r] + g[c] ) + b ),  g = (x@W)*dinv
// dinv = rsqrt(indeg+1) (self-loops folded in analytically).
// Round 21: index double-buffer in both gather loops. The per-thread chain
// was idx->rows->idx->rows (one extra full load latency per 8 edges);
// now ix[k+1] (two int4) is issued BEFORE batch k's 8 row loads, so the
// index latency hides under the row loads. 8 rows + 1 index pair in
// flight/thread; tail = up to two 4-batches from the prefetched pair
// (sentinel pads make all reads safe and exact-zero). Math bit-identical.
// Discriminator: if null, gathers are purely random-request-throughput-bound
// (with r13/r18/r19/r20 nulls) -> structural floor, declare roofline.
// Negative results bank (do NOT retry): LDS-atomic accumulation (r11/12);
// degree-ranked perm (r13); global counting scatter (r14: 17x write amp);
// 32KB col cache in fill / NBUCKET=782 (r15); gather-before-matmul /
// 2-lane gather1 (r18); row size / cache tier of gathered rows (r18 null).

constexpr int NN  = 100000;
constexpr int FIN = 16;
constexpr int FH  = 32;   // hidden
constexpr int FO  = 16;   // layer-2 out

constexpr int BK      = 256;                     // nodes per bucket (col>>8)
constexpr int NBUCKET = (NN + BK - 1) / BK;      // 391
constexpr int CHUNK   = 8192;                    // edges per block (fill)
constexpr int CAP     = 5632;                    // bucket capacity (mean 4092 + pad, +18 sigma)

static __device__ __forceinline__ int pack2(float a, float b) {
    __half2 t = __float22half2_rn(make_float2(a, b));
    return *reinterpret_cast<int*>(&t);
}
static __device__ __forceinline__ float2 unpack2(int v) {
    __half2 t = *reinterpret_cast<__half2*>(&v);
    return __half22float2(t);
}

// ---- phase A: bucket fill into fixed segments. Per-block run reservation.
// bcursor[b] is a RELATIVE cursor (memset to 0); absolute = b*CAP + rel. ----
__global__ __launch_bounds__(1024) void bucket_fill_kernel(
        const int* __restrict__ row, const int* __restrict__ col,
        int* __restrict__ bcursor, int* __restrict__ srow, int E) {
    __shared__ int bcnt[NBUCKET];
    __shared__ int bcur[NBUCKET];
    int t = threadIdx.x;
    int e0 = blockIdx.x * CHUNK;
    int m = E - e0; if (m > CHUNK) m = CHUNK;
    for (int b = t; b < NBUCKET; b += 1024) bcnt[b] = 0;
    __syncthreads();
    for (int i = t; i < m; i += 1024)
        atomicAdd(&bcnt[col[e0 + i] >> 8], 1);
    __syncthreads();
    for (int b = t; b < NBUCKET; b += 1024) {
        int v = bcnt[b];
        bcur[b] = v ? (b * CAP + atomicAdd(&bcursor[b], v)) : 0;  // absolute run start
    }
    __syncthreads();
    for (int i = t; i < m; i += 1024) {
        int c = col[e0 + i];
        int r = row[e0 + i];
        int p = atomicAdd(&bcur[c >> 8], 1);
        srow[p] = ((c & (BK - 1)) << 17) | r;          // pack (c_local, r); r < 2^17
    }
}

// ---- phase B: per-bucket LDS counting sort; emits off/cnt/dinv AND g1 rows.
// 1024 threads: sort phases use all; mm1 split by feature-quarter (t>>8).
// Offsets padded to multiples of 4; pad slots hold sentinel NN.
// Block 0 additionally zeroes the sentinel rows g1[NN], g2[NN].
__global__ __launch_bounds__(1024) void bucket_sort_mm1_kernel(
        const int* __restrict__ bcursor, int* __restrict__ srow,
        int* __restrict__ off, int* __restrict__ cnt, float* __restrict__ dinv,
        const float* __restrict__ x, const float* __restrict__ W1,
        __half* __restrict__ g1, __half* __restrict__ g2, int n) {
    __shared__ int ebuf[CAP];
    __shared__ int sorted[CAP];
    __shared__ int cnt2[BK];
    __shared__ float sdi[BK];
    __shared__ int wsum[4];
    __shared__ int wbase[4];
    __shared__ int Mtot;
    __shared__ float w1[FIN * FH];
    int t = threadIdx.x;
    for (int i = t; i < FIN * FH; i += 1024) w1[i] = W1[i];
    if (blockIdx.x == 0 && t < 6) {                    // sentinel rows = 0
        if (t < 4) ((int4*)(g1 + (long long)NN * FH))[t] = make_int4(0, 0, 0, 0);
        else       ((int4*)(g2 + (long long)NN * FO))[t - 4] = make_int4(0, 0, 0, 0);
    }
    int lo = blockIdx.x << 8;
    int nodes = n - lo; if (nodes > BK) nodes = BK;
    int s0 = blockIdx.x * CAP;
    int m = bcursor[blockIdx.x];                       // relative count == edges here
    if (m > CAP) m = CAP;                              // paranoia guard (never hit)
    if (m < 0)  m = 0;
    for (int i = t; i < m; i += 1024) ebuf[i] = srow[s0 + i];
    if (t < BK) cnt2[t] = 0;
    __syncthreads();
    for (int i = t; i < m; i += 1024) atomicAdd(&cnt2[ebuf[i] >> 17], 1);
    __syncthreads();
    int v = 0, pv = 0, s = 0, excl = 0;
    if (t < BK) {
        v  = cnt2[t];
        pv = (v + 3) & ~3;                             // padded count
        s  = pv;
        #pragma unroll
        for (int d = 1; d < 64; d <<= 1) {             // inclusive wave scan
            int u = __shfl_up(s, d, 64);
            if ((t & 63) >= d) s += u;
        }
        if ((t & 63) == 63) wsum[t >> 6] = s;
    }
    __syncthreads();
    if (t < 4) {
        int b = 0;
        for (int k = 0; k < t; k++) b += wsum[k];
        wbase[t] = b;
    }
    __syncthreads();
    if (t < BK) {
        excl = s + wbase[t >> 6] - pv;                 // exclusive padded prefix
        cnt2[t] = excl;                                // cursor for scatter
        float di = rsqrtf((float)v + 1.0f);
        sdi[t] = di;
        if (t < nodes) {
            off[lo + t]  = s0 + excl;
            cnt[lo + t]  = v;
            dinv[lo + t] = di;
        }
        if (t == BK - 1) Mtot = excl + pv;             // total padded length
    }
    __syncthreads();
    for (int i = t; i < m; i += 1024) {
        int pvv = ebuf[i];
        int p = atomicAdd(&cnt2[pvv >> 17], 1);
        sorted[p] = pvv & 0x1FFFF;
    }
    __syncthreads();
    if (t < BK) {                                      // sentinel pads
        for (int p = excl + v; p < excl + pv; p++) sorted[p] = NN;
    }
    __syncthreads();
    int M = Mtot; if (M > CAP) M = CAP;
    for (int i = t; i < M; i += 1024) srow[s0 + i] = sorted[i];
    // ---- fused mm1 (split): lane=t>>8 computes feature-quarter of node t&255 ----
    int lane = t >> 8;                                 // 0..3
    int nd0  = t & 255;
    if (nd0 < nodes) {
        int nd = lo + nd0;
        float di = sdi[nd0];
        float xi[FIN];
        const float4* xv = (const float4*)(x + (long long)nd * FIN);
        #pragma unroll
        for (int i = 0; i < FIN / 4; i++) {
            float4 vv = xv[i];
            xi[4*i] = vv.x; xi[4*i+1] = vv.y; xi[4*i+2] = vv.z; xi[4*i+3] = vv.w;
        }
        float h[8];
        #pragma unroll
        for (int j = 0; j < 8; j++) h[j] = 0.f;
        const float* wl = w1 + lane * 8;
        #pragma unroll
        for (int i = 0; i < FIN; i++) {
            float xs = xi[i];
            #pragma unroll
            for (int j = 0; j < 8; j++) h[j] += xs * wl[i * FH + j];
        }
        ((int4*)(g1 + (long long)nd * FH))[lane] =
            make_int4(pack2(h[0]*di, h[1]*di), pack2(h[2]*di, h[3]*di),
                      pack2(h[4]*di, h[5]*di), pack2(h[6]*di, h[7]*di));
    }
}

// accumulate one 16B fragment (8 fp16) into acc[8]
#define ACC_ROW(R)                                          \
    { float2 u;                                             \
      u = unpack2((R).x); acc[0] += u.x; acc[1] += u.y;     \
      u = unpack2((R).y); acc[2] += u.x; acc[3] += u.y;     \
      u = unpack2((R).z); acc[4] += u.x; acc[5] += u.y;     \
      u = unpack2((R).w); acc[6] += u.x; acc[7] += u.y; }

// ---- fused gather layer1 (fp16 rows) + relu/bias + mm2 + scale -> g2 (fp16) ----
// block = 256 threads = 64 nodes x 4 lanes (lane = 8 feats = int4 = 16 B).
// Padded CSR, 8 rows + 1 prefetched index pair in flight per thread.
constexpr int XS = 36;   // LDS stride: 16B-aligned writes, 2-way (free) reads
__global__ __launch_bounds__(256) void gather_mm2_kernel(
        const int* __restrict__ off, const int* __restrict__ cnt,
        const int* __restrict__ srow, const __half* __restrict__ g1,
        const float* __restrict__ dinv, const float* __restrict__ b1,
        const float* __restrict__ W2, __half* __restrict__ g2, int n) {
    __shared__ float xs[64 * XS];          // 64 nodes x 32 feats (stride 36)
    __shared__ float w[FH * FO];           // 32x16
    __shared__ float bb[FH];
    int t = threadIdx.x;
    for (int i = t; i < FH * FO; i += 256) w[i] = W2[i];
    if (t < FH) bb[t] = b1[t];
    int nl = t >> 2;                       // node-local 0..63
    int q = t & 3;                         // 8-feat group
    int node = blockIdx.x * 64 + nl;
    bool live = node < n;
    float acc[8] = {0.f,0.f,0.f,0.f,0.f,0.f,0.f,0.f};
    float di = 0.f;
    if (live) {
        di = dinv[node];
        {   // self-loop seed
            int4 raw = ((const int4*)(g1 + (long long)node * FH))[q];
            float2 f0 = unpack2(raw.x), f1 = unpack2(raw.y);
            float2 f2 = unpack2(raw.z), f3 = unpack2(raw.w);
            acc[0] = f0.x; acc[1] = f0.y; acc[2] = f1.x; acc[3] = f1.y;
            acc[4] = f2.x; acc[5] = f2.y; acc[6] = f3.x; acc[7] = f3.y;
        }
        int s = off[node];
        int m = cnt[node];
        if (m > 0) {
            // double-buffered indices: batch k's rows overlap batch k+1's idx
            int4 ixA = *(const int4*)(srow + s);
            int4 ixB = *(const int4*)(srow + s + 4);   // safe: slack segment
            int i = 0;
            for (; i + 8 < m; i += 8) {
                int4 ixA2 = *(const int4*)(srow + s + i + 8);
                int4 ixB2 = *(const int4*)(srow + s + i + 12);
                int4 ra = ((const int4*)(g1 + (long long)ixA.x * FH))[q];
                int4 rb = ((const int4*)(g1 + (long long)ixA.y * FH))[q];
                int4 rc = ((const int4*)(g1 + (long long)ixA.z * FH))[q];
                int4 rd = ((const int4*)(g1 + (long long)ixA.w * FH))[q];
                int4 re = ((const int4*)(g1 + (long long)ixB.x * FH))[q];
                int4 rf = ((const int4*)(g1 + (long long)ixB.y * FH))[q];
                int4 rg = ((const int4*)(g1 + (long long)ixB.z * FH))[q];
                int4 rh = ((const int4*)(g1 + (long long)ixB.w * FH))[q];
                ACC_ROW(ra); ACC_ROW(rb); ACC_ROW(rc); ACC_ROW(rd);
                ACC_ROW(re); ACC_ROW(rf); ACC_ROW(rg); ACC_ROW(rh);
                ixA = ixA2; ixB = ixB2;
            }
            {   // tail batch 1 (always exists; pads are sentinel-zero)
                int4 ra = ((const int4*)(g1 + (long long)ixA.x * FH))[q];
                int4 rb = ((const int4*)(g1 + (long long)ixA.y * FH))[q];
                int4 rc = ((const int4*)(g1 + (long long)ixA.z * FH))[q];
                int4 rd = ((const int4*)(g1 + (long long)ixA.w * FH))[q];
                ACC_ROW(ra); ACC_ROW(rb); ACC_ROW(rc); ACC_ROW(rd);
            }
            if (i + 4 < m) {               // tail batch 2
                int4 ra = ((const int4*)(g1 + (long long)ixB.x * FH))[q];
                int4 rb = ((const int4*)(g1 + (long long)ixB.y * FH))[q];
                int4 rc = ((const int4*)(g1 + (long long)ixB.z * FH))[q];
                int4 rd = ((const int4*)(g1 + (long long)ixB.w * FH))[q];
                ACC_ROW(ra); ACC_ROW(rb); ACC_ROW(rc); ACC_ROW(rd);
            }
        }
    }
    __syncthreads();                       // w/bb loaded; also before xs write
    if (live) {
        // x1[8q..8q+7] = relu(acc*di + b1)
        float* xr = xs + nl * XS + 8 * q;
        #pragma unroll
        for (int j = 0; j < 8; j++) {
            float a = acc[j] * di + bb[8*q + j];
            xr[j] = a > 0.f ? a : 0.f;
        }
    }
    __syncthreads();
    if (live) {
        // lane q computes outputs k = 4q..4q+3 of x1 @ W2 (FO=16)
        const float* xr = xs + nl * XS;
        int k0 = 4 * q;
        float o0 = 0.f, o1 = 0.f, o2 = 0.f, o3 = 0.f;
        #pragma unroll
        for (int j = 0; j < FH; j++) {
            float xj = xr[j];
            const float* wr = w + j * FO + k0;
            o0 += xj * wr[0];
            o1 += xj * wr[1];
            o2 += xj * wr[2];
            o3 += xj * wr[3];
        }
        ((int2*)(g2 + (long long)node * FO))[q] =
            make_int2(pack2(o0 * di, o1 * di), pack2(o2 * di, o3 * di));
    }
}

// ---- fused gather layer2 (fp16 rows) + relu/bias + fc -> out ----
// block = 256 threads = 128 nodes x 2 lanes; padded CSR, 8 rows + 1
// prefetched index pair in flight per thread.
__global__ __launch_bounds__(256) void gather_fc_kernel(
        const int* __restrict__ off, const int* __restrict__ cnt,
        const int* __restrict__ srow, const __half* __restrict__ g2,
        const float* __restrict__ dinv, const float* __restrict__ b2,
        const float* __restrict__ fcW, const float* __restrict__ fcb,
        float* __restrict__ out, int n) {
    __shared__ float w[FO];
    __shared__ float bb[FO];
    __shared__ float fb;
    int t = threadIdx.x;
    if (t < FO) { w[t] = fcW[t]; bb[t] = b2[t]; }
    if (t == 0) fb = fcb[0];
    __syncthreads();
    int node = blockIdx.x * 128 + (t >> 1);
    int q = t & 1;
    if (node >= n) return;
    float di = dinv[node];
    float acc[8];
    {   // self-loop seed
        int4 raw = ((const int4*)(g2 + (long long)node * FO))[q];
        float2 f0 = unpack2(raw.x), f1 = unpack2(raw.y);
        float2 f2 = unpack2(raw.z), f3 = unpack2(raw.w);
        acc[0] = f0.x; acc[1] = f0.y; acc[2] = f1.x; acc[3] = f1.y;
        acc[4] = f2.x; acc[5] = f2.y; acc[6] = f3.x; acc[7] = f3.y;
    }
    int s = off[node];
    int m = cnt[node];
    if (m > 0) {
        int4 ixA = *(const int4*)(srow + s);
        int4 ixB = *(const int4*)(srow + s + 4);       // safe: slack segment
        int i = 0;
        for (; i + 8 < m; i += 8) {
            int4 ixA2 = *(const int4*)(srow + s + i + 8);
            int4 ixB2 = *(const int4*)(srow + s + i + 12);
            int4 ra = ((const int4*)(g2 + (long long)ixA.x * FO))[q];
            int4 rb = ((const int4*)(g2 + (long long)ixA.y * FO))[q];
            int4 rc = ((const int4*)(g2 + (long long)ixA.z * FO))[q];
            int4 rd = ((const int4*)(g2 + (long long)ixA.w * FO))[q];
            int4 re = ((const int4*)(g2 + (long long)ixB.x * FO))[q];
            int4 rf = ((const int4*)(g2 + (long long)ixB.y * FO))[q];
            int4 rg = ((const int4*)(g2 + (long long)ixB.z * FO))[q];
            int4 rh = ((const int4*)(g2 + (long long)ixB.w * FO))[q];
            ACC_ROW(ra); ACC_ROW(rb); ACC_ROW(rc); ACC_ROW(rd);
            ACC_ROW(re); ACC_ROW(rf); ACC_ROW(rg); ACC_ROW(rh);
            ixA = ixA2; ixB = ixB2;
        }
        {   // tail batch 1
            int4 ra = ((const int4*)(g2 + (long long)ixA.x * FO))[q];
            int4 rb = ((const int4*)(g2 + (long long)ixA.y * FO))[q];
            int4 rc = ((const int4*)(g2 + (long long)ixA.z * FO))[q];
            int4 rd = ((const int4*)(g2 + (long long)ixA.w * FO))[q];
            ACC_ROW(ra); ACC_ROW(rb); ACC_ROW(rc); ACC_ROW(rd);
        }
        if (i + 4 < m) {                   // tail batch 2
            int4 ra = ((const int4*)(g2 + (long long)ixB.x * FO))[q];
            int4 rb = ((const int4*)(g2 + (long long)ixB.y * FO))[q];
            int4 rc = ((const int4*)(g2 + (long long)ixB.z * FO))[q];
            int4 rd = ((const int4*)(g2 + (long long)ixB.w * FO))[q];
            ACC_ROW(ra); ACC_ROW(rb); ACC_ROW(rc); ACC_ROW(rd);
        }
    }
    // x2 = relu(acc*di + b2[8q..]); partial dot with fcW
    float p = 0.f;
    #pragma unroll
    for (int j = 0; j < 8; j++) {
        float a = acc[j] * di + bb[8*q + j];
        p += (a > 0.f ? a : 0.f) * w[8*q + j];
    }
    p += __shfl_down(p, 1, 2);             // reduce the node's 2 lanes
    if (q == 0) out[node] = p + fb;
}

extern "C" void kernel_launch(void* const* d_in, const int* in_sizes, int n_in,
                              void* d_out, int out_size, void* d_ws, size_t ws_size,
                              hipStream_t stream) {
    const int*   edge = (const int*)d_in[0];        // [2, E] int32
    const float* x    = (const float*)d_in[1];      // [N, 16]
    const float* W1   = (const float*)d_in[2];      // [16, 32]
    const float* b1   = (const float*)d_in[3];      // [32]
    const float* W2   = (const float*)d_in[4];      // [32, 16]
    const float* b2   = (const float*)d_in[5];      // [16]
    const float* fcW  = (const float*)d_in[6];      // [16, 1]
    const float* fcb  = (const float*)d_in[7];      // [1]
    float* out = (float*)d_out;

    const int E = in_sizes[0] / 2;                  // 1600000
    const int n = NN;
    const int* row = edge;
    const int* col = edge + E;

    // workspace layout (4-byte units), regions 128-elem aligned:
    const size_t nA = (size_t)((n + 127) & ~127);
    char* wsb = (char*)d_ws;
    int*   cnt     = (int*)wsb;                     // n ints (per-node degree)
    int*   off     = cnt + nA;                      // n ints (padded CSR offsets)
    float* dinv    = (float*)(off + nA);            // n floats
    int*   bcursor = (int*)(dinv + nA);             // NBUCKET ints (pad 512)
    int*   srow    = bcursor + 512;                 // (NBUCKET+1)*CAP ints (+slack seg)
    int*   srowEnd = srow + (size_t)(NBUCKET + 1) * CAP;
    __half* g1     = (__half*)srowEnd;              // (n+1)*FH halfs (sentinel row at NN)
    __half* g2     = g1 + (size_t)(n + 1) * FH;     // (n+1)*FO halfs (sentinel row at NN)

    const int nChunkBlocks = (E + CHUNK - 1) / CHUNK;   // 196

    // 1. bcursor = 0 (relative cursors)
    hipMemsetAsync(bcursor, 0, 512 * sizeof(int), stream);
    // 2. phase A: bucket fill into fixed segments; per-block run reservation
    bucket_fill_kernel<<<nChunkBlocks, 1024, 0, stream>>>(row, col, bcursor, srow, E);
    // 3. phase B: per-bucket LDS counting sort (padded offsets) + sentinels + mm1
    bucket_sort_mm1_kernel<<<NBUCKET, 1024, 0, stream>>>(bcursor, srow, off, cnt, dinv, x, W1, g1, g2, n);
    // 4. fused gather1 + relu/bias + mm2 + scale -> g2   (64 nodes/block, dbuf idx)
    gather_mm2_kernel<<<(n + 63) / 64, 256, 0, stream>>>(off, cnt, srow, g1, dinv, b1, W2, g2, n);
    // 5. fused gather2 + relu/bias + fc -> out            (128 nodes/block, dbuf idx)
    gather_fc_kernel<<<(n + 127) / 128, 256, 0, stream>>>(off, cnt, srow, g2, dinv, b2, fcW, fcb, out, n);
}

// Round 12
// 137.895 us; speedup vs baseline: 1.0744x; 1.0007x over previous
//
#include <hip/hip_runtime.h>
#include <hip/hip_fp16.h>

// GCN 2-layer forward. N=100000 nodes, E=1600000 directed edges.
// out[c] = relu( dinv[c] * ( sum_{r->c} g[r] + g[c] ) + b ),  g = (x@W)*dinv
// dinv = rsqrt(indeg+1) (self-loops folded in analytically).
// Round 22: gather_fc reshaped to the WINNING gather configuration.
// r17 vs r18 A/B showed these gathers respond to wave count: 64 nodes x
// 4 lanes (6252 waves, 76% occ) beat 128 nodes x 2 lanes (3128, 38%).
// gather_fc always ran the losing shape. Now: 64 nodes x 4 lanes/block,
// lane = 4 feats = int2 (8B); per-wave distinct-line count unchanged,
// in-flight request capacity doubles. Index dbuf kept (4 lanes load the
// same int4 -> same-address merge). Reduce = 2-step shfl_xor over 4 lanes.
// Pre-commit: if delta < 2us, all gather levers are exhausted -> ROOFLINE.
// Negative results bank (do NOT retry): LDS-atomic accumulation (r11/12);
// degree-ranked perm (r13); global counting scatter (r14: 17x write amp);
// 32KB col cache in fill / NBUCKET=782 (r15); gather-before-matmul /
// 2-lane gather1 (r18); row size / cache tier (r18 null); deeper MLP
// beyond 8+idx-dbuf (r21: -1.5us only).

constexpr int NN  = 100000;
constexpr int FIN = 16;
constexpr int FH  = 32;   // hidden
constexpr int FO  = 16;   // layer-2 out

constexpr int BK      = 256;                     // nodes per bucket (col>>8)
constexpr int NBUCKET = (NN + BK - 1) / BK;      // 391
constexpr int CHUNK   = 8192;                    // edges per block (fill)
constexpr int CAP     = 5632;                    // bucket capacity (mean 4092 + pad, +18 sigma)

static __device__ __forceinline__ int pack2(float a, float b) {
    __half2 t = __float22half2_rn(make_float2(a, b));
    return *reinterpret_cast<int*>(&t);
}
static __device__ __forceinline__ float2 unpack2(int v) {
    __half2 t = *reinterpret_cast<__half2*>(&v);
    return __half22float2(t);
}

// ---- phase A: bucket fill into fixed segments. Per-block run reservation.
// bcursor[b] is a RELATIVE cursor (memset to 0); absolute = b*CAP + rel. ----
__global__ __launch_bounds__(1024) void bucket_fill_kernel(
        const int* __restrict__ row, const int* __restrict__ col,
        int* __restrict__ bcursor, int* __restrict__ srow, int E) {
    __shared__ int bcnt[NBUCKET];
    __shared__ int bcur[NBUCKET];
    int t = threadIdx.x;
    int e0 = blockIdx.x * CHUNK;
    int m = E - e0; if (m > CHUNK) m = CHUNK;
    for (int b = t; b < NBUCKET; b += 1024) bcnt[b] = 0;
    __syncthreads();
    for (int i = t; i < m; i += 1024)
        atomicAdd(&bcnt[col[e0 + i] >> 8], 1);
    __syncthreads();
    for (int b = t; b < NBUCKET; b += 1024) {
        int v = bcnt[b];
        bcur[b] = v ? (b * CAP + atomicAdd(&bcursor[b], v)) : 0;  // absolute run start
    }
    __syncthreads();
    for (int i = t; i < m; i += 1024) {
        int c = col[e0 + i];
        int r = row[e0 + i];
        int p = atomicAdd(&bcur[c >> 8], 1);
        srow[p] = ((c & (BK - 1)) << 17) | r;          // pack (c_local, r); r < 2^17
    }
}

// ---- phase B: per-bucket LDS counting sort; emits off/cnt/dinv AND g1 rows.
// 1024 threads: sort phases use all; mm1 split by feature-quarter (t>>8).
// Offsets padded to multiples of 4; pad slots hold sentinel NN.
// Block 0 additionally zeroes the sentinel rows g1[NN], g2[NN].
__global__ __launch_bounds__(1024) void bucket_sort_mm1_kernel(
        const int* __restrict__ bcursor, int* __restrict__ srow,
        int* __restrict__ off, int* __restrict__ cnt, float* __restrict__ dinv,
        const float* __restrict__ x, const float* __restrict__ W1,
        __half* __restrict__ g1, __half* __restrict__ g2, int n) {
    __shared__ int ebuf[CAP];
    __shared__ int sorted[CAP];
    __shared__ int cnt2[BK];
    __shared__ float sdi[BK];
    __shared__ int wsum[4];
    __shared__ int wbase[4];
    __shared__ int Mtot;
    __shared__ float w1[FIN * FH];
    int t = threadIdx.x;
    for (int i = t; i < FIN * FH; i += 1024) w1[i] = W1[i];
    if (blockIdx.x == 0 && t < 6) {                    // sentinel rows = 0
        if (t < 4) ((int4*)(g1 + (long long)NN * FH))[t] = make_int4(0, 0, 0, 0);
        else       ((int4*)(g2 + (long long)NN * FO))[t - 4] = make_int4(0, 0, 0, 0);
    }
    int lo = blockIdx.x << 8;
    int nodes = n - lo; if (nodes > BK) nodes = BK;
    int s0 = blockIdx.x * CAP;
    int m = bcursor[blockIdx.x];                       // relative count == edges here
    if (m > CAP) m = CAP;                              // paranoia guard (never hit)
    if (m < 0)  m = 0;
    for (int i = t; i < m; i += 1024) ebuf[i] = srow[s0 + i];
    if (t < BK) cnt2[t] = 0;
    __syncthreads();
    for (int i = t; i < m; i += 1024) atomicAdd(&cnt2[ebuf[i] >> 17], 1);
    __syncthreads();
    int v = 0, pv = 0, s = 0, excl = 0;
    if (t < BK) {
        v  = cnt2[t];
        pv = (v + 3) & ~3;                             // padded count
        s  = pv;
        #pragma unroll
        for (int d = 1; d < 64; d <<= 1) {             // inclusive wave scan
            int u = __shfl_up(s, d, 64);
            if ((t & 63) >= d) s += u;
        }
        if ((t & 63) == 63) wsum[t >> 6] = s;
    }
    __syncthreads();
    if (t < 4) {
        int b = 0;
        for (int k = 0; k < t; k++) b += wsum[k];
        wbase[t] = b;
    }
    __syncthreads();
    if (t < BK) {
        excl = s + wbase[t >> 6] - pv;                 // exclusive padded prefix
        cnt2[t] = excl;                                // cursor for scatter
        float di = rsqrtf((float)v + 1.0f);
        sdi[t] = di;
        if (t < nodes) {
            off[lo + t]  = s0 + excl;
            cnt[lo + t]  = v;
            dinv[lo + t] = di;
        }
        if (t == BK - 1) Mtot = excl + pv;             // total padded length
    }
    __syncthreads();
    for (int i = t; i < m; i += 1024) {
        int pvv = ebuf[i];
        int p = atomicAdd(&cnt2[pvv >> 17], 1);
        sorted[p] = pvv & 0x1FFFF;
    }
    __syncthreads();
    if (t < BK) {                                      // sentinel pads
        for (int p = excl + v; p < excl + pv; p++) sorted[p] = NN;
    }
    __syncthreads();
    int M = Mtot; if (M > CAP) M = CAP;
    for (int i = t; i < M; i += 1024) srow[s0 + i] = sorted[i];
    // ---- fused mm1 (split): lane=t>>8 computes feature-quarter of node t&255 ----
    int lane = t >> 8;                                 // 0..3
    int nd0  = t & 255;
    if (nd0 < nodes) {
        int nd = lo + nd0;
        float di = sdi[nd0];
        float xi[FIN];
        const float4* xv = (const float4*)(x + (long long)nd * FIN);
        #pragma unroll
        for (int i = 0; i < FIN / 4; i++) {
            float4 vv = xv[i];
            xi[4*i] = vv.x; xi[4*i+1] = vv.y; xi[4*i+2] = vv.z; xi[4*i+3] = vv.w;
        }
        float h[8];
        #pragma unroll
        for (int j = 0; j < 8; j++) h[j] = 0.f;
        const float* wl = w1 + lane * 8;
        #pragma unroll
        for (int i = 0; i < FIN; i++) {
            float xs = xi[i];
            #pragma unroll
            for (int j = 0; j < 8; j++) h[j] += xs * wl[i * FH + j];
        }
        ((int4*)(g1 + (long long)nd * FH))[lane] =
            make_int4(pack2(h[0]*di, h[1]*di), pack2(h[2]*di, h[3]*di),
                      pack2(h[4]*di, h[5]*di), pack2(h[6]*di, h[7]*di));
    }
}

// accumulate one 16B fragment (8 fp16) into acc[8]
#define ACC_ROW(R)                                          \
    { float2 u;                                             \
      u = unpack2((R).x); acc[0] += u.x; acc[1] += u.y;     \
      u = unpack2((R).y); acc[2] += u.x; acc[3] += u.y;     \
      u = unpack2((R).z); acc[4] += u.x; acc[5] += u.y;     \
      u = unpack2((R).w); acc[6] += u.x; acc[7] += u.y; }

// accumulate one 8B fragment (4 fp16) into acc[4]
#define ACC_ROW2(R)                                         \
    { float2 u;                                             \
      u = unpack2((R).x); acc[0] += u.x; acc[1] += u.y;     \
      u = unpack2((R).y); acc[2] += u.x; acc[3] += u.y; }

// ---- fused gather layer1 (fp16 rows) + relu/bias + mm2 + scale -> g2 (fp16) ----
// block = 256 threads = 64 nodes x 4 lanes (lane = 8 feats = int4 = 16 B).
// Padded CSR, 8 rows + 1 prefetched index pair in flight per thread.
constexpr int XS = 36;   // LDS stride: 16B-aligned writes, 2-way (free) reads
__global__ __launch_bounds__(256) void gather_mm2_kernel(
        const int* __restrict__ off, const int* __restrict__ cnt,
        const int* __restrict__ srow, const __half* __restrict__ g1,
        const float* __restrict__ dinv, const float* __restrict__ b1,
        const float* __restrict__ W2, __half* __restrict__ g2, int n) {
    __shared__ float xs[64 * XS];          // 64 nodes x 32 feats (stride 36)
    __shared__ float w[FH * FO];           // 32x16
    __shared__ float bb[FH];
    int t = threadIdx.x;
    for (int i = t; i < FH * FO; i += 256) w[i] = W2[i];
    if (t < FH) bb[t] = b1[t];
    int nl = t >> 2;                       // node-local 0..63
    int q = t & 3;                         // 8-feat group
    int node = blockIdx.x * 64 + nl;
    bool live = node < n;
    float acc[8] = {0.f,0.f,0.f,0.f,0.f,0.f,0.f,0.f};
    float di = 0.f;
    if (live) {
        di = dinv[node];
        {   // self-loop seed
            int4 raw = ((const int4*)(g1 + (long long)node * FH))[q];
            float2 f0 = unpack2(raw.x), f1 = unpack2(raw.y);
            float2 f2 = unpack2(raw.z), f3 = unpack2(raw.w);
            acc[0] = f0.x; acc[1] = f0.y; acc[2] = f1.x; acc[3] = f1.y;
            acc[4] = f2.x; acc[5] = f2.y; acc[6] = f3.x; acc[7] = f3.y;
        }
        int s = off[node];
        int m = cnt[node];
        if (m > 0) {
            // double-buffered indices: batch k's rows overlap batch k+1's idx
            int4 ixA = *(const int4*)(srow + s);
            int4 ixB = *(const int4*)(srow + s + 4);   // safe: slack segment
            int i = 0;
            for (; i + 8 < m; i += 8) {
                int4 ixA2 = *(const int4*)(srow + s + i + 8);
                int4 ixB2 = *(const int4*)(srow + s + i + 12);
                int4 ra = ((const int4*)(g1 + (long long)ixA.x * FH))[q];
                int4 rb = ((const int4*)(g1 + (long long)ixA.y * FH))[q];
                int4 rc = ((const int4*)(g1 + (long long)ixA.z * FH))[q];
                int4 rd = ((const int4*)(g1 + (long long)ixA.w * FH))[q];
                int4 re = ((const int4*)(g1 + (long long)ixB.x * FH))[q];
                int4 rf = ((const int4*)(g1 + (long long)ixB.y * FH))[q];
                int4 rg = ((const int4*)(g1 + (long long)ixB.z * FH))[q];
                int4 rh = ((const int4*)(g1 + (long long)ixB.w * FH))[q];
                ACC_ROW(ra); ACC_ROW(rb); ACC_ROW(rc); ACC_ROW(rd);
                ACC_ROW(re); ACC_ROW(rf); ACC_ROW(rg); ACC_ROW(rh);
                ixA = ixA2; ixB = ixB2;
            }
            {   // tail batch 1 (always exists; pads are sentinel-zero)
                int4 ra = ((const int4*)(g1 + (long long)ixA.x * FH))[q];
                int4 rb = ((const int4*)(g1 + (long long)ixA.y * FH))[q];
                int4 rc = ((const int4*)(g1 + (long long)ixA.z * FH))[q];
                int4 rd = ((const int4*)(g1 + (long long)ixA.w * FH))[q];
                ACC_ROW(ra); ACC_ROW(rb); ACC_ROW(rc); ACC_ROW(rd);
            }
            if (i + 4 < m) {               // tail batch 2
                int4 ra = ((const int4*)(g1 + (long long)ixB.x * FH))[q];
                int4 rb = ((const int4*)(g1 + (long long)ixB.y * FH))[q];
                int4 rc = ((const int4*)(g1 + (long long)ixB.z * FH))[q];
                int4 rd = ((const int4*)(g1 + (long long)ixB.w * FH))[q];
                ACC_ROW(ra); ACC_ROW(rb); ACC_ROW(rc); ACC_ROW(rd);
            }
        }
    }
    __syncthreads();                       // w/bb loaded; also before xs write
    if (live) {
        // x1[8q..8q+7] = relu(acc*di + b1)
        float* xr = xs + nl * XS + 8 * q;
        #pragma unroll
        for (int j = 0; j < 8; j++) {
            float a = acc[j] * di + bb[8*q + j];
            xr[j] = a > 0.f ? a : 0.f;
        }
    }
    __syncthreads();
    if (live) {
        // lane q computes outputs k = 4q..4q+3 of x1 @ W2 (FO=16)
        const float* xr = xs + nl * XS;
        int k0 = 4 * q;
        float o0 = 0.f, o1 = 0.f, o2 = 0.f, o3 = 0.f;
        #pragma unroll
        for (int j = 0; j < FH; j++) {
            float xj = xr[j];
            const float* wr = w + j * FO + k0;
            o0 += xj * wr[0];
            o1 += xj * wr[1];
            o2 += xj * wr[2];
            o3 += xj * wr[3];
        }
        ((int2*)(g2 + (long long)node * FO))[q] =
            make_int2(pack2(o0 * di, o1 * di), pack2(o2 * di, o3 * di));
    }
}

// ---- fused gather layer2 (fp16 rows) + relu/bias + fc -> out ----
// block = 256 threads = 64 nodes x 4 lanes (lane = 4 feats = int2 = 8 B).
// Padded CSR, 8 rows + 1 prefetched index pair in flight per thread.
// 1563 blocks -> 6252 waves (76% occ) vs the old 2-lane shape's 3128 (38%).
__global__ __launch_bounds__(256) void gather_fc_kernel(
        const int* __restrict__ off, const int* __restrict__ cnt,
        const int* __restrict__ srow, const __half* __restrict__ g2,
        const float* __restrict__ dinv, const float* __restrict__ b2,
        const float* __restrict__ fcW, const float* __restrict__ fcb,
        float* __restrict__ out, int n) {
    __shared__ float w[FO];
    __shared__ float bb[FO];
    __shared__ float fb;
    int t = threadIdx.x;
    if (t < FO) { w[t] = fcW[t]; bb[t] = b2[t]; }
    if (t == 0) fb = fcb[0];
    __syncthreads();
    int nl = t >> 2;                       // node-local 0..63
    int q = t & 3;                         // 4-feat group
    int node = blockIdx.x * 64 + nl;
    if (node >= n) return;
    float di = dinv[node];
    float acc[4];
    {   // self-loop seed
        int2 raw = ((const int2*)(g2 + (long long)node * FO))[q];
        float2 f0 = unpack2(raw.x), f1 = unpack2(raw.y);
        acc[0] = f0.x; acc[1] = f0.y; acc[2] = f1.x; acc[3] = f1.y;
    }
    int s = off[node];
    int m = cnt[node];
    if (m > 0) {
        int4 ixA = *(const int4*)(srow + s);           // 4 lanes same addr -> merge
        int4 ixB = *(const int4*)(srow + s + 4);       // safe: slack segment
        int i = 0;
        for (; i + 8 < m; i += 8) {
            int4 ixA2 = *(const int4*)(srow + s + i + 8);
            int4 ixB2 = *(const int4*)(srow + s + i + 12);
            int2 ra = ((const int2*)(g2 + (long long)ixA.x * FO))[q];
            int2 rb = ((const int2*)(g2 + (long long)ixA.y * FO))[q];
            int2 rc = ((const int2*)(g2 + (long long)ixA.z * FO))[q];
            int2 rd = ((const int2*)(g2 + (long long)ixA.w * FO))[q];
            int2 re = ((const int2*)(g2 + (long long)ixB.x * FO))[q];
            int2 rf = ((const int2*)(g2 + (long long)ixB.y * FO))[q];
            int2 rg = ((const int2*)(g2 + (long long)ixB.z * FO))[q];
            int2 rh = ((const int2*)(g2 + (long long)ixB.w * FO))[q];
            ACC_ROW2(ra); ACC_ROW2(rb); ACC_ROW2(rc); ACC_ROW2(rd);
            ACC_ROW2(re); ACC_ROW2(rf); ACC_ROW2(rg); ACC_ROW2(rh);
            ixA = ixA2; ixB = ixB2;
        }
        {   // tail batch 1 (always exists; pads are sentinel-zero)
            int2 ra = ((const int2*)(g2 + (long long)ixA.x * FO))[q];
            int2 rb = ((const int2*)(g2 + (long long)ixA.y * FO))[q];
            int2 rc = ((const int2*)(g2 + (long long)ixA.z * FO))[q];
            int2 rd = ((const int2*)(g2 + (long long)ixA.w * FO))[q];
            ACC_ROW2(ra); ACC_ROW2(rb); ACC_ROW2(rc); ACC_ROW2(rd);
        }
        if (i + 4 < m) {                   // tail batch 2
            int2 ra = ((const int2*)(g2 + (long long)ixB.x * FO))[q];
            int2 rb = ((const int2*)(g2 + (long long)ixB.y * FO))[q];
            int2 rc = ((const int2*)(g2 + (long long)ixB.z * FO))[q];
            int2 rd = ((const int2*)(g2 + (long long)ixB.w * FO))[q];
            ACC_ROW2(ra); ACC_ROW2(rb); ACC_ROW2(rc); ACC_ROW2(rd);
        }
    }
    // x2 = relu(acc*di + b2[4q..]); partial dot with fcW; 4-lane xor reduce
    float p = 0.f;
    #pragma unroll
    for (int j = 0; j < 4; j++) {
        float a = acc[j] * di + bb[4*q + j];
        p += (a > 0.f ? a : 0.f) * w[4*q + j];
    }
    p += __shfl_xor(p, 1);
    p += __shfl_xor(p, 2);
    if (q == 0) out[node] = p + fb;
}

extern "C" void kernel_launch(void* const* d_in, const int* in_sizes, int n_in,
                              void* d_out, int out_size, void* d_ws, size_t ws_size,
                              hipStream_t stream) {
    const int*   edge = (const int*)d_in[0];        // [2, E] int32
    const float* x    = (const float*)d_in[1];      // [N, 16]
    const float* W1   = (const float*)d_in[2];      // [16, 32]
    const float* b1   = (const float*)d_in[3];      // [32]
    const float* W2   = (const float*)d_in[4];      // [32, 16]
    const float* b2   = (const float*)d_in[5];      // [16]
    const float* fcW  = (const float*)d_in[6];      // [16, 1]
    const float* fcb  = (const float*)d_in[7];      // [1]
    float* out = (float*)d_out;

    const int E = in_sizes[0] / 2;                  // 1600000
    const int n = NN;
    const int* row = edge;
    const int* col = edge + E;

    // workspace layout (4-byte units), regions 128-elem aligned:
    const size_t nA = (size_t)((n + 127) & ~127);
    char* wsb = (char*)d_ws;
    int*   cnt     = (int*)wsb;                     // n ints (per-node degree)
    int*   off     = cnt + nA;                      // n ints (padded CSR offsets)
    float* dinv    = (float*)(off + nA);            // n floats
    int*   bcursor = (int*)(dinv + nA);             // NBUCKET ints (pad 512)
    int*   srow    = bcursor + 512;                 // (NBUCKET+1)*CAP ints (+slack seg)
    int*   srowEnd = srow + (size_t)(NBUCKET + 1) * CAP;
    __half* g1     = (__half*)srowEnd;              // (n+1)*FH halfs (sentinel row at NN)
    __half* g2     = g1 + (size_t)(n + 1) * FH;     // (n+1)*FO halfs (sentinel row at NN)

    const int nChunkBlocks = (E + CHUNK - 1) / CHUNK;   // 196

    // 1. bcursor = 0 (relative cursors)
    hipMemsetAsync(bcursor, 0, 512 * sizeof(int), stream);
    // 2. phase A: bucket fill into fixed segments; per-block run reservation
    bucket_fill_kernel<<<nChunkBlocks, 1024, 0, stream>>>(row, col, bcursor, srow, E);
    // 3. phase B: per-bucket LDS counting sort (padded offsets) + sentinels + mm1
    bucket_sort_mm1_kernel<<<NBUCKET, 1024, 0, stream>>>(bcursor, srow, off, cnt, dinv, x, W1, g1, g2, n);
    // 4. fused gather1 + relu/bias + mm2 + scale -> g2   (64 nodes/block, dbuf idx)
    gather_mm2_kernel<<<(n + 63) / 64, 256, 0, stream>>>(off, cnt, srow, g1, dinv, b1, W2, g2, n);
    // 5. fused gather2 + relu/bias + fc -> out            (64 nodes/block, 4 lanes)
    gather_fc_kernel<<<(n + 63) / 64, 256, 0, stream>>>(off, cnt, srow, g2, dinv, b2, fcW, fcb, out, n);
}